// Round 3
// baseline (1885.123 us; speedup 1.0000x reference)
//
#include <hip/hip_runtime.h>
#include <hip/hip_bf16.h>

#define N_NODES 50000
#define N_EDGES 1600000
#define N_GRAPHS 256
#define NEG_SLOPE 0.2f
#define BN_EPS 1e-5f

typedef __hip_bfloat16 bf16;

__device__ __forceinline__ float b2f(bf16 v){ return __bfloat162float(v); }
__device__ __forceinline__ bf16 f2b(float v){ return __float2bfloat16(v); }
__device__ __forceinline__ float us2f(unsigned short u){ return __uint_as_float(((unsigned)u)<<16); }
// mode: 1 => external float tensors are f32, 0 => bf16
__device__ __forceinline__ float ldF(const void* p, size_t i, int m){
  return m ? ((const float*)p)[i] : b2f(((const bf16*)p)[i]);
}
__device__ __forceinline__ float sane(float v){
  return (v == v && fabsf(v) < 1e30f) ? v : 0.f;
}

// ---------------- dtype detection ----------------
__global__ void k_detect(const void* x, int* flag){
  if(threadIdx.x == 0 && blockIdx.x == 0){
    const unsigned short* u = (const unsigned short*)x;
    int insane = 0;
    for(int i=0;i<1024;i++){
      float v = fabsf(us2f(u[i]));
      if(!(v > 1e-6f && v < 1e4f)) insane++;   // NaN compares false -> insane
    }
    flag[0] = (insane > 128) ? 1 : 0;  // 1 => data is f32
    flag[1] = 1;                       // constant "f32" flag for internal buffers
  }
}

// ---------------- weight bank conversion ----------------
#define NSEG 33
struct Bank { const void* p[NSEG]; int n[NSEG]; int off[NSEG]; };

__global__ void k_convert(Bank b, const int* mode, float* out){
  int seg = blockIdx.y;
  int i = blockIdx.x*256 + threadIdx.x;
  int m = *mode;
  if(i < b.n[seg]) out[b.off[seg] + i] = ldF(b.p[seg], i, m);
}

// ---------------- CSR build ----------------
__global__ void k_count(const int* __restrict__ dst, int* __restrict__ cnt){
  int e = blockIdx.x*256 + threadIdx.x;
  if(e < N_EDGES){
    int d = dst[e]; if((unsigned)d >= N_NODES) d = 0;
    atomicAdd(&cnt[d], 1);
  }
}

__global__ void k_blocksum(const int* __restrict__ cnt, int* __restrict__ bsum){
  __shared__ int s[256];
  int i = blockIdx.x*256 + threadIdx.x;
  s[threadIdx.x] = (i < N_NODES) ? cnt[i] : 0;
  __syncthreads();
  for(int o=128;o>0;o>>=1){ if(threadIdx.x<o) s[threadIdx.x]+=s[threadIdx.x+o]; __syncthreads(); }
  if(threadIdx.x==0) bsum[blockIdx.x]=s[0];
}

__global__ void k_scan_bsum(const int* __restrict__ bsum, int* __restrict__ bofs, int nb){
  __shared__ int s[256];
  int t = threadIdx.x;
  s[t] = (t<nb) ? bsum[t] : 0;
  __syncthreads();
  for(int o=1;o<256;o<<=1){ int v=(t>=o)?s[t-o]:0; __syncthreads(); s[t]+=v; __syncthreads(); }
  bofs[t] = (t==0) ? 0 : s[t-1];
}

__global__ void k_scan_write(const int* __restrict__ cnt, const int* __restrict__ bofs, int* __restrict__ rp){
  __shared__ int s[256];
  int t = threadIdx.x; int i = blockIdx.x*256 + t;
  int v = (i<N_NODES) ? cnt[i] : 0;
  s[t]=v; __syncthreads();
  for(int o=1;o<256;o<<=1){ int a=(t>=o)?s[t-o]:0; __syncthreads(); s[t]+=a; __syncthreads(); }
  if(i<N_NODES) rp[i+1] = s[t] + bofs[blockIdx.x];
  if(i==0) rp[0]=0;
}

__global__ void k_fill(const int* __restrict__ src, const int* __restrict__ dst,
                       const int* __restrict__ rp, int* __restrict__ fill,
                       int* __restrict__ col_src, int* __restrict__ eidA){
  int e = blockIdx.x*256 + threadIdx.x;
  if(e >= N_EDGES) return;
  int d = dst[e]; if((unsigned)d >= N_NODES) d = 0;
  int p = atomicAdd(&fill[d], 1);
  int slot = rp[d] + p;
  if((unsigned)slot < N_EDGES){
    int sv = src[e]; if((unsigned)sv >= N_NODES) sv = 0;
    col_src[slot] = sv;
    eidA[slot] = e;
  }
}

// loop_attr (mean of incoming edge_attr) + GCN dinv
__global__ void k_node_misc(const int* __restrict__ rp, const int* __restrict__ eidA,
                            const void* __restrict__ ea, const int* __restrict__ mode,
                            float* __restrict__ loop_attr, float* __restrict__ dinv){
  int n = blockIdx.x*256 + threadIdx.x;
  if(n >= N_NODES) return;
  int m = *mode;
  int s = rp[n], e = rp[n+1];
  if((unsigned)s > N_EDGES){ s=0; e=0; }
  if(e < s || (unsigned)e > N_EDGES) e = s;
  float acc[8];
  #pragma unroll
  for(int k=0;k<8;k++) acc[k]=0.f;
  for(int i=s;i<e;i++){
    int eid = eidA[i]; if((unsigned)eid >= N_EDGES) eid = 0;
    #pragma unroll
    for(int k=0;k<8;k++) acc[k] += ldF(ea, (size_t)eid*8 + k, m);
  }
  float c = (float)(e - s);
  float inv = 1.f / fmaxf(c, 1.f);
  #pragma unroll
  for(int k=0;k<8;k++) loop_attr[n*8+k] = acc[k]*inv;
  dinv[n] = rsqrtf(c + 1.f);
}

// w_e[h][k] = sum_d We[k, h*64+d] * a_e[h, d]  (f32 bank inputs)
__global__ void k_we(const float* __restrict__ We1, const float* __restrict__ ae1,
                     const float* __restrict__ We2, const float* __restrict__ ae2,
                     float* __restrict__ w_e){
  int t = threadIdx.x;
  if(t < 32){
    int h = t >> 3, k = t & 7;
    float s = 0.f;
    for(int d=0;d<64;d++) s += We1[k*256 + h*64 + d] * ae1[h*64 + d];
    w_e[t] = s;
  } else if(t < 40){
    int k = t - 32;
    float s = 0.f;
    for(int d=0;d<64;d++) s += We2[k*64 + d] * ae2[d];
    w_e[t] = s;
  }
}

// ---------------- GEMM: C[N, coff:coff+64] = A[N,KIN] @ W[:, woff:woff+64] ----------------
template<int KIN>
__global__ void k_gemm(const void* __restrict__ A, int lda, const int* __restrict__ amode,
                       const float* __restrict__ W, int ldw, int woff,
                       float* __restrict__ C, int ldc, int coff){
  int idx = blockIdx.x*256 + threadIdx.x;
  if(idx >= N_NODES*64) return;
  int mm = idx >> 6, j = idx & 63;
  int am = *amode;
  float s = 0.f;
  #pragma unroll 8
  for(int k=0;k<KIN;k++) s += ldF(A, (size_t)mm*lda + k, am) * W[k*ldw + woff + j];
  C[(size_t)mm*ldc + coff + j] = s;
}

// alpha_src / alpha_dst per node (single head slice)
__global__ void k_al1(const float* __restrict__ hp, const float* __restrict__ asrc,
                      const float* __restrict__ adst,
                      float* __restrict__ als, float* __restrict__ ald){
  int n = blockIdx.x*256 + threadIdx.x;
  if(n >= N_NODES) return;
  const float* row = hp + (size_t)n*64;
  float ss=0.f, sd=0.f;
  #pragma unroll 8
  for(int d=0;d<64;d++){ float v=row[d]; ss += v*asrc[d]; sd += v*adst[d]; }
  als[n]=ss; ald[n]=sd;
}

// ---------------- GAT aggregate (single head, softmax over incoming + self loop) ----------------
__global__ __launch_bounds__(64) void k_gat_agg1(
    const int* __restrict__ rp, const int* __restrict__ col_src, const int* __restrict__ eidA,
    const void* __restrict__ ea, const int* __restrict__ mode,
    const float* __restrict__ hp,
    const float* __restrict__ als, const float* __restrict__ ald,
    const float* __restrict__ loop_attr, const float* __restrict__ we8,
    const float* __restrict__ bias64, float* __restrict__ out, int ldc, int coff){
  int n = blockIdx.x; int t = threadIdx.x;
  __shared__ float sw[64];
  __shared__ int   ssrc[64];
  __shared__ float sE, sSelf;
  int am = *mode;
  int s0 = rp[n], e0 = rp[n+1];
  if((unsigned)s0 > N_EDGES){ s0=0; e0=0; }
  if(e0 < s0 || (unsigned)e0 > N_EDGES) e0 = s0;
  float aldn = ald[n];
  if(t == 0){
    float dot = 0.f;
    #pragma unroll
    for(int k=0;k<8;k++) dot += loop_attr[n*8+k]*we8[k];
    float sc = als[n] + aldn + dot;
    sc = sc > 0.f ? sc : NEG_SLOPE*sc;
    sc = fminf(sc, 30.f);
    float w = expf(sc);
    sSelf = w; sE = w;
  }
  __syncthreads();
  float acc = sSelf * hp[(size_t)n*64 + t];
  for(int base = s0; base < e0; base += 64){
    int m = min(64, e0 - base);
    if(t < m){
      int sn  = col_src[base+t]; if((unsigned)sn  >= N_NODES) sn  = 0;
      int eid = eidA[base+t];    if((unsigned)eid >= N_EDGES) eid = 0;
      float dot = 0.f;
      #pragma unroll
      for(int k=0;k<8;k++) dot += ldF(ea, (size_t)eid*8 + k, am) * we8[k];
      float sc = als[sn] + aldn + dot;
      sc = sc > 0.f ? sc : NEG_SLOPE*sc;
      sc = fminf(sc, 30.f);
      float w = expf(sc);
      sw[t] = w; ssrc[t] = sn;
      atomicAdd(&sE, w);
    }
    __syncthreads();
    for(int i=0;i<m;i++) acc += sw[i] * hp[(size_t)ssrc[i]*64 + t];
    __syncthreads();
  }
  out[(size_t)n*ldc + coff + t] = acc / sE + bias64[t];
}

// ---------------- GCN aggregate ----------------
__global__ __launch_bounds__(64) void k_gcn_agg(
    const int* __restrict__ rp, const int* __restrict__ col_src,
    const float* __restrict__ dinv, const float* __restrict__ gp,
    const float* __restrict__ bias, float* __restrict__ out){
  int n = blockIdx.x; int t = threadIdx.x;
  __shared__ float sw[64];
  __shared__ int   ssrc[64];
  int s0 = rp[n], e0 = rp[n+1];
  if((unsigned)s0 > N_EDGES){ s0=0; e0=0; }
  if(e0 < s0 || (unsigned)e0 > N_EDGES) e0 = s0;
  float dn = dinv[n];
  float acc = dn * gp[(size_t)n*64 + t];
  for(int base = s0; base < e0; base += 64){
    int m = min(64, e0 - base);
    if(t < m){
      int sn = col_src[base+t]; if((unsigned)sn >= N_NODES) sn = 0;
      ssrc[t]=sn; sw[t]=dinv[sn];
    }
    __syncthreads();
    for(int i=0;i<m;i++) acc += sw[i] * gp[(size_t)ssrc[i]*64 + t];
    __syncthreads();
  }
  out[(size_t)n*64 + t] = dn*acc + bias[t];
}

// ---------------- BN stats + apply (f32 data, sanitized) ----------------
template<int C>
__global__ void k_colstats(const float* __restrict__ X, float* __restrict__ sums){
  constexpr int RPB = 128;
  constexpr int RSTEP = 256 / C;
  int c = threadIdx.x % C;
  int r0 = threadIdx.x / C;
  int rbeg = blockIdx.x * RPB;
  int rend = min(N_NODES, rbeg + RPB);
  float s = 0.f, q = 0.f;
  for(int r = rbeg + r0; r < rend; r += RSTEP){
    float v = sane(X[(size_t)r*C + c]);
    s += v; q += v*v;
  }
  atomicAdd(&sums[c], s);
  atomicAdd(&sums[C + c], q);
}

template<int C>
__global__ void k_bn_relu(float* __restrict__ X, const float* __restrict__ sums,
                          const float* __restrict__ g, const float* __restrict__ b){
  int idx = blockIdx.x*256 + threadIdx.x;
  if(idx >= N_NODES*C) return;
  int c = idx % C;
  const float invN = 1.0f / (float)N_NODES;
  float mean = sums[c]*invN;
  float var = fmaxf(sums[C+c]*invN - mean*mean, 0.f);
  float y = (sane(X[idx])-mean)*rsqrtf(var + BN_EPS)*g[c] + b[c];
  X[idx] = fmaxf(y, 0.f);
}

// ---------------- mean pool ----------------
__global__ void k_pool(const float* __restrict__ h, const int* __restrict__ batch,
                       float* __restrict__ psum, float* __restrict__ pcnt){
  int idx = blockIdx.x*256 + threadIdx.x;
  if(idx >= N_NODES*64) return;
  int n = idx >> 6, c = idx & 63;
  int g = batch[n]; if((unsigned)g >= N_GRAPHS) g = 0;
  atomicAdd(&psum[g*64 + c], h[idx]);
  if(c == 0) atomicAdd(&pcnt[g], 1.f);
}

// ---------------- head MLPs + output writeback (mode-aware store) ----------------
__device__ __forceinline__ void stO(void* o, size_t i, float v, int m){
  if(m) ((float*)o)[i] = v; else ((bf16*)o)[i] = f2b(v);
}

__global__ __launch_bounds__(128) void k_head(
    const float* __restrict__ psum, const float* __restrict__ pcnt,
    const float* __restrict__ exf,
    const float* __restrict__ Wex1, const float* __restrict__ bex1,
    const float* __restrict__ Wex2, const float* __restrict__ bex2,
    const float* __restrict__ Wc1, const float* __restrict__ bc1,
    const float* __restrict__ Wc2, const float* __restrict__ bc2,
    const int* __restrict__ mode, void* __restrict__ dout){
  int g = blockIdx.x; int t = threadIdx.x;
  int m0 = *mode;
  __shared__ float ci[128];
  __shared__ float e1[64];
  __shared__ float comb[128];
  __shared__ float red[128];
  if(t < 64){
    float c = fmaxf(pcnt[g], 1.f);
    float xp = sane(psum[g*64 + t]) / c;
    ci[t] = xp;
    stO(dout, 256 + (size_t)g*64 + t, xp, m0);
  } else {
    int j = t - 64;
    float s = bex1[j];
    for(int k=0;k<32;k++) s += exf[g*32 + k] * Wex1[k*64 + j];
    e1[j] = fmaxf(s, 0.f);
  }
  __syncthreads();
  if(t >= 64){
    int j = t - 64;
    float s = bex2[j];
    for(int k=0;k<64;k++) s += e1[k] * Wex2[k*64 + j];
    ci[64 + j] = fmaxf(s, 0.f);
  }
  __syncthreads();
  {
    float s = bc1[t];
    for(int k=0;k<128;k++) s += ci[k] * Wc1[k*128 + t];
    s = fmaxf(s, 0.f);
    comb[t] = s;
    stO(dout, 256 + 16384 + (size_t)g*128 + t, s, m0);
  }
  __syncthreads();
  red[t] = comb[t] * Wc2[t];
  __syncthreads();
  for(int o=64;o>0;o>>=1){ if(t<o) red[t]+=red[t+o]; __syncthreads(); }
  if(t==0) stO(dout, g, red[0] + bc2[0], m0);
}

// ---------------- launch ----------------
extern "C" void kernel_launch(void* const* d_in, const int* in_sizes, int n_in,
                              void* d_out, int out_size, void* d_ws, size_t ws_size,
                              hipStream_t stream){
  const void* x    = d_in[0];
  const void* ea   = d_in[1];
  const int* ei    = (const int*)d_in[3];
  const int* batch = (const int*)d_in[4];
  const int* src = ei;
  const int* dst = ei + N_EDGES;

  char* base = (char*)d_ws;
  size_t off = 0;
  auto alloc = [&](size_t bytes) -> void* {
    void* r = base + off;
    off += (bytes + 255) & ~(size_t)255;
    return r;
  };
  // zero-init region first (one memset)
  int*   cnt    = (int*)  alloc((size_t)N_NODES*4);
  int*   fill   = (int*)  alloc((size_t)N_NODES*4);
  float* bnstat = (float*)alloc(4096);
  float* pool   = (float*)alloc((size_t)(N_GRAPHS*64 + N_GRAPHS)*4);
  size_t zbytes = off;
  int*   rp      = (int*)  alloc((size_t)(N_NODES+1)*4);
  int*   bsum    = (int*)  alloc(256*4);
  int*   bofs    = (int*)  alloc(256*4);
  int*   col_src = (int*)  alloc((size_t)N_EDGES*4);
  int*   eidA    = (int*)  alloc((size_t)N_EDGES*4);
  float* loop_attr=(float*)alloc((size_t)N_NODES*8*4);
  float* dinv    = (float*)alloc((size_t)N_NODES*4);
  float* w_e     = (float*)alloc(64*4);
  float* als     = (float*)alloc((size_t)N_NODES*4);
  float* ald     = (float*)alloc((size_t)N_NODES*4);
  int*   mode    = (int*)  alloc(8);          // [0]=detected, [1]=1 (f32 const)
  float* wbank   = (float*)alloc(80000*4);
  float* hp      = (float*)alloc((size_t)N_NODES*64*4);
  float* out1    = (float*)alloc((size_t)N_NODES*256*4);
  // ~80 MB total

  float* out2 = out1;                         // aliases (out1 dead when written)
  float* out3 = out1 + (size_t)N_NODES*64;
  float* out4 = out1 + (size_t)N_NODES*128;
  float* bn1 = bnstat;
  float* bn2 = bnstat + 512;
  float* bn3 = bnstat + 640;
  float* bn4 = bnstat + 768;
  float* psum = pool;
  float* pcnt = pool + N_GRAPHS*64;
  int* fone = mode + 1;

  // ---- weight bank ----
  // seg order: exf, W1,as1,ad1,We1,ae1,b1,g1,be1, W2,as2,ad2,We2,ae2,b2,g2,be2,
  //            Wg1,bg1,g3,be3, Wg2,bg2,g4,be4, Wex1,bex1,Wex2,bex2, Wc1,bc1,Wc2,bc2
  const int segidx[NSEG] = {2, 5,6,7,8,9,10,11,12, 13,14,15,16,17,18,19,20,
                            21,22,23,24, 25,26,27,28, 29,30,31,32, 33,34,35,36};
  const int segn[NSEG] = {8192, 16384,256,256,2048,256,256,256,256,
                          16384,64,64,512,64,64,64,64,
                          4096,64,64,64, 4096,64,64,64,
                          2048,64,4096,64, 16384,128,128,1};
  Bank bk;
  int offs[NSEG]; int acc0 = 0;
  for(int i=0;i<NSEG;i++){ bk.p[i]=d_in[segidx[i]]; bk.n[i]=segn[i]; bk.off[i]=acc0; offs[i]=acc0; acc0+=segn[i]; }
  const float* f_exf = wbank + offs[0];
  const float* fW1 = wbank+offs[1]; const float* fas1 = wbank+offs[2]; const float* fad1 = wbank+offs[3];
  const float* fWe1= wbank+offs[4]; const float* fae1 = wbank+offs[5]; const float* fb1  = wbank+offs[6];
  const float* fg1 = wbank+offs[7]; const float* fbe1 = wbank+offs[8];
  const float* fW2 = wbank+offs[9]; const float* fas2 = wbank+offs[10]; const float* fad2 = wbank+offs[11];
  const float* fWe2= wbank+offs[12]; const float* fae2 = wbank+offs[13]; const float* fb2 = wbank+offs[14];
  const float* fg2 = wbank+offs[15]; const float* fbe2 = wbank+offs[16];
  const float* fWg1= wbank+offs[17]; const float* fbg1 = wbank+offs[18]; const float* fg3 = wbank+offs[19];
  const float* fbe3= wbank+offs[20];
  const float* fWg2= wbank+offs[21]; const float* fbg2 = wbank+offs[22]; const float* fg4 = wbank+offs[23];
  const float* fbe4= wbank+offs[24];
  const float* fWex1=wbank+offs[25]; const float* fbex1= wbank+offs[26];
  const float* fWex2=wbank+offs[27]; const float* fbex2= wbank+offs[28];
  const float* fWc1= wbank+offs[29]; const float* fbc1 = wbank+offs[30];
  const float* fWc2= wbank+offs[31]; const float* fbc2 = wbank+offs[32];

  const int nbN  = (N_NODES + 255)/256;
  const int nbE  = (N_EDGES + 255)/256;
  const int nb64 = (N_NODES*64 + 255)/256;

  hipMemsetAsync(d_ws, 0, zbytes, stream);
  k_detect<<<1,64,0,stream>>>(x, mode);
  {
    dim3 g((16384+255)/256, NSEG);
    k_convert<<<g,256,0,stream>>>(bk, mode, wbank);
  }
  k_count<<<nbE,256,0,stream>>>(dst, cnt);
  k_blocksum<<<nbN,256,0,stream>>>(cnt, bsum);
  k_scan_bsum<<<1,256,0,stream>>>(bsum, bofs, nbN);
  k_scan_write<<<nbN,256,0,stream>>>(cnt, bofs, rp);
  k_fill<<<nbE,256,0,stream>>>(src, dst, rp, fill, col_src, eidA);
  k_node_misc<<<nbN,256,0,stream>>>(rp, eidA, ea, mode, loop_attr, dinv);
  k_we<<<1,64,0,stream>>>(fWe1, fae1, fWe2, fae2, w_e);

  // GAT layer 1 (4 heads sequentially, concat -> out1 [N,256])
  for(int h=0; h<4; h++){
    k_gemm<64><<<nb64,256,0,stream>>>(x, 64, mode, fW1, 256, h*64, hp, 64, 0);
    k_al1<<<nbN,256,0,stream>>>(hp, fas1 + h*64, fad1 + h*64, als, ald);
    k_gat_agg1<<<N_NODES,64,0,stream>>>(rp, col_src, eidA, ea, mode, hp,
                                        als, ald, loop_attr, w_e + h*8,
                                        fb1 + h*64, out1, 256, h*64);
  }
  k_colstats<256><<<(N_NODES+127)/128,256,0,stream>>>(out1, bn1);
  k_bn_relu<256><<<(N_NODES*256+255)/256,256,0,stream>>>(out1, bn1, fg1, fbe1);

  // GAT layer 2 (1 head, mean==identity -> out2 [N,64])
  k_gemm<256><<<nb64,256,0,stream>>>(out1, 256, fone, fW2, 64, 0, hp, 64, 0);
  k_al1<<<nbN,256,0,stream>>>(hp, fas2, fad2, als, ald);
  k_gat_agg1<<<N_NODES,64,0,stream>>>(rp, col_src, eidA, ea, mode, hp,
                                      als, ald, loop_attr, w_e + 32, fb2, out2, 64, 0);
  k_colstats<64><<<(N_NODES+127)/128,256,0,stream>>>(out2, bn2);
  k_bn_relu<64><<<nb64,256,0,stream>>>(out2, bn2, fg2, fbe2);

  // GCN layer 1
  k_gemm<64><<<nb64,256,0,stream>>>(out2, 64, fone, fWg1, 64, 0, hp, 64, 0);
  k_gcn_agg<<<N_NODES,64,0,stream>>>(rp, col_src, dinv, hp, fbg1, out3);
  k_colstats<64><<<(N_NODES+127)/128,256,0,stream>>>(out3, bn3);
  k_bn_relu<64><<<nb64,256,0,stream>>>(out3, bn3, fg3, fbe3);

  // GCN layer 2
  k_gemm<64><<<nb64,256,0,stream>>>(out3, 64, fone, fWg2, 64, 0, hp, 64, 0);
  k_gcn_agg<<<N_NODES,64,0,stream>>>(rp, col_src, dinv, hp, fbg2, out4);
  k_colstats<64><<<(N_NODES+127)/128,256,0,stream>>>(out4, bn4);
  k_bn_relu<64><<<nb64,256,0,stream>>>(out4, bn4, fg4, fbe4);

  // pool + head
  k_pool<<<nb64,256,0,stream>>>(out4, batch, psum, pcnt);
  k_head<<<N_GRAPHS,128,0,stream>>>(psum, pcnt, f_exf, fWex1, fbex1, fWex2, fbex2,
                                    fWc1, fbc1, fWc2, fbc2, mode, d_out);
}

// Round 4
// 1660.353 us; speedup vs baseline: 1.1354x; 1.1354x over previous
//
#include <hip/hip_runtime.h>
#include <hip/hip_bf16.h>

#define N_NODES 50000
#define N_EDGES 1600000
#define N_GRAPHS 256
#define NEG_SLOPE 0.2f
#define BN_EPS 1e-5f

typedef __hip_bfloat16 bf16;

__device__ __forceinline__ float b2f(bf16 v){ return __bfloat162float(v); }
__device__ __forceinline__ bf16 f2b(float v){ return __float2bfloat16(v); }
__device__ __forceinline__ float us2f(unsigned short u){ return __uint_as_float(((unsigned)u)<<16); }
// mode: 1 => external float tensors are f32, 0 => bf16
__device__ __forceinline__ float ldF(const void* p, size_t i, int m){
  return m ? ((const float*)p)[i] : b2f(((const bf16*)p)[i]);
}
__device__ __forceinline__ float sane(float v){
  return (v == v && fabsf(v) < 1e30f) ? v : 0.f;
}

// ---------------- dtype detection ----------------
__global__ void k_detect(const void* x, int* flag){
  if(threadIdx.x == 0 && blockIdx.x == 0){
    const unsigned short* u = (const unsigned short*)x;
    int insane = 0;
    for(int i=0;i<1024;i++){
      float v = fabsf(us2f(u[i]));
      if(!(v > 1e-6f && v < 1e4f)) insane++;   // NaN compares false -> insane
    }
    flag[0] = (insane > 128) ? 1 : 0;  // 1 => data is f32
    flag[1] = 1;                       // constant "f32" flag for internal buffers
  }
}

// ---------------- weight bank conversion ----------------
#define NSEG 33
struct Bank { const void* p[NSEG]; int n[NSEG]; int off[NSEG]; };

__global__ void k_convert(Bank b, const int* mode, float* out){
  int seg = blockIdx.y;
  int i = blockIdx.x*256 + threadIdx.x;
  int m = *mode;
  if(i < b.n[seg]) out[b.off[seg] + i] = ldF(b.p[seg], i, m);
}

// ---------------- CSR build ----------------
__global__ void k_count(const int* __restrict__ dst, int* __restrict__ cnt){
  int e = blockIdx.x*256 + threadIdx.x;
  if(e < N_EDGES){
    int d = dst[e]; if((unsigned)d >= N_NODES) d = 0;
    atomicAdd(&cnt[d], 1);
  }
}

__global__ void k_blocksum(const int* __restrict__ cnt, int* __restrict__ bsum){
  __shared__ int s[256];
  int i = blockIdx.x*256 + threadIdx.x;
  s[threadIdx.x] = (i < N_NODES) ? cnt[i] : 0;
  __syncthreads();
  for(int o=128;o>0;o>>=1){ if(threadIdx.x<o) s[threadIdx.x]+=s[threadIdx.x+o]; __syncthreads(); }
  if(threadIdx.x==0) bsum[blockIdx.x]=s[0];
}

__global__ void k_scan_bsum(const int* __restrict__ bsum, int* __restrict__ bofs, int nb){
  __shared__ int s[256];
  int t = threadIdx.x;
  s[t] = (t<nb) ? bsum[t] : 0;
  __syncthreads();
  for(int o=1;o<256;o<<=1){ int v=(t>=o)?s[t-o]:0; __syncthreads(); s[t]+=v; __syncthreads(); }
  bofs[t] = (t==0) ? 0 : s[t-1];
}

__global__ void k_scan_write(const int* __restrict__ cnt, const int* __restrict__ bofs, int* __restrict__ rp){
  __shared__ int s[256];
  int t = threadIdx.x; int i = blockIdx.x*256 + t;
  int v = (i<N_NODES) ? cnt[i] : 0;
  s[t]=v; __syncthreads();
  for(int o=1;o<256;o<<=1){ int a=(t>=o)?s[t-o]:0; __syncthreads(); s[t]+=a; __syncthreads(); }
  if(i<N_NODES) rp[i+1] = s[t] + bofs[blockIdx.x];
  if(i==0) rp[0]=0;
}

__global__ void k_fill(const int* __restrict__ src, const int* __restrict__ dst,
                       const int* __restrict__ rp, int* __restrict__ fill,
                       int* __restrict__ col_src, int* __restrict__ eidA){
  int e = blockIdx.x*256 + threadIdx.x;
  if(e >= N_EDGES) return;
  int d = dst[e]; if((unsigned)d >= N_NODES) d = 0;
  int p = atomicAdd(&fill[d], 1);
  int slot = rp[d] + p;
  if((unsigned)slot < N_EDGES){
    int sv = src[e]; if((unsigned)sv >= N_NODES) sv = 0;
    col_src[slot] = sv;
    eidA[slot] = e;
  }
}

// loop_attr (mean of incoming edge_attr) + GCN dinv
__global__ void k_node_misc(const int* __restrict__ rp, const int* __restrict__ eidA,
                            const void* __restrict__ ea, const int* __restrict__ mode,
                            float* __restrict__ loop_attr, float* __restrict__ dinv){
  int n = blockIdx.x*256 + threadIdx.x;
  if(n >= N_NODES) return;
  int m = *mode;
  int s = rp[n], e = rp[n+1];
  if((unsigned)s > N_EDGES){ s=0; e=0; }
  if(e < s || (unsigned)e > N_EDGES) e = s;
  float acc[8];
  #pragma unroll
  for(int k=0;k<8;k++) acc[k]=0.f;
  for(int i=s;i<e;i++){
    int eid = eidA[i]; if((unsigned)eid >= N_EDGES) eid = 0;
    #pragma unroll
    for(int k=0;k<8;k++) acc[k] += ldF(ea, (size_t)eid*8 + k, m);
  }
  float c = (float)(e - s);
  float inv = 1.f / fmaxf(c, 1.f);
  #pragma unroll
  for(int k=0;k<8;k++) loop_attr[n*8+k] = acc[k]*inv;
  dinv[n] = rsqrtf(c + 1.f);
}

// w_e[h][k] = sum_d We[k, h*64+d] * a_e[h, d]  (f32 bank inputs)
__global__ void k_we(const float* __restrict__ We1, const float* __restrict__ ae1,
                     const float* __restrict__ We2, const float* __restrict__ ae2,
                     float* __restrict__ w_e){
  int t = threadIdx.x;
  if(t < 32){
    int h = t >> 3, k = t & 7;
    float s = 0.f;
    for(int d=0;d<64;d++) s += We1[k*256 + h*64 + d] * ae1[h*64 + d];
    w_e[t] = s;
  } else if(t < 40){
    int k = t - 32;
    float s = 0.f;
    for(int d=0;d<64;d++) s += We2[k*64 + d] * ae2[d];
    w_e[t] = s;
  }
}

// ---------------- tiled GEMM: C[:, coff:coff+64] = A[:,:KIN] @ W[:, woff:woff+64] ----------------
// BM=64 rows, BN=64 cols, BK=64, 256 threads, 4x4 register block per thread.
// A is f32 or bf16 per runtime *amode (wave-uniform branch around staging only).
template<int KIN>
__global__ __launch_bounds__(256) void k_gemm_t(
    const void* __restrict__ A, int lda, const int* __restrict__ amode,
    const float* __restrict__ W, int ldw, int woff,
    float* __restrict__ C, int ldc, int coff, int M)
{
  __shared__ float As[64][68];   // [m][k], stride 68 -> 16B-aligned rows, 2-way banks max
  __shared__ float Ws[64][64];   // [k][j]
  const int tid = threadIdx.x;
  const int bm  = blockIdx.x * 64;
  const int tx  = tid & 15;      // col group (4 cols)
  const int ty  = tid >> 4;      // row group (4 rows)
  const int am  = *amode;
  float acc[4][4] = {};

  for(int k0 = 0; k0 < KIN; k0 += 64){
    // ---- stage A tile (64 rows x 64 k) ----
    if(am){
      const float* Af = (const float*)A;
      #pragma unroll
      for(int f = tid; f < 1024; f += 256){
        int r = f >> 4, kq = f & 15;
        int row = bm + r;
        float4 v = make_float4(0.f,0.f,0.f,0.f);
        if(row < M) v = *(const float4*)&Af[(size_t)row*lda + k0 + 4*kq];
        *(float4*)&As[r][4*kq] = v;
      }
    } else {
      const bf16* Ab = (const bf16*)A;
      #pragma unroll
      for(int f = tid; f < 1024; f += 256){
        int r = f >> 4, kq = f & 15;
        int row = bm + r;
        float4 v = make_float4(0.f,0.f,0.f,0.f);
        if(row < M){
          const bf16* p = &Ab[(size_t)row*lda + k0 + 4*kq];
          v = make_float4(b2f(p[0]), b2f(p[1]), b2f(p[2]), b2f(p[3]));
        }
        *(float4*)&As[r][4*kq] = v;
      }
    }
    // ---- stage W tile (64 k x 64 j) ----
    #pragma unroll
    for(int g = tid; g < 1024; g += 256){
      int kr = g >> 4, jq = g & 15;
      *(float4*)&Ws[kr][4*jq] = *(const float4*)&W[(size_t)(k0+kr)*ldw + woff + 4*jq];
    }
    __syncthreads();
    // ---- compute ----
    #pragma unroll
    for(int k = 0; k < 64; k += 4){
      float4 av[4], wv[4];
      #pragma unroll
      for(int r=0;r<4;r++) av[r] = *(const float4*)&As[4*ty + r][k];
      #pragma unroll
      for(int kk=0;kk<4;kk++) wv[kk] = *(const float4*)&Ws[k + kk][4*tx];
      #pragma unroll
      for(int r=0;r<4;r++){
        const float a0=av[r].x, a1=av[r].y, a2=av[r].z, a3=av[r].w;
        acc[r][0] += a0*wv[0].x + a1*wv[1].x + a2*wv[2].x + a3*wv[3].x;
        acc[r][1] += a0*wv[0].y + a1*wv[1].y + a2*wv[2].y + a3*wv[3].y;
        acc[r][2] += a0*wv[0].z + a1*wv[1].z + a2*wv[2].z + a3*wv[3].z;
        acc[r][3] += a0*wv[0].w + a1*wv[1].w + a2*wv[2].w + a3*wv[3].w;
      }
    }
    __syncthreads();
  }
  // ---- store ----
  #pragma unroll
  for(int r=0;r<4;r++){
    int row = bm + 4*ty + r;
    if(row < M){
      float4 v = make_float4(acc[r][0], acc[r][1], acc[r][2], acc[r][3]);
      *(float4*)&C[(size_t)row*ldc + coff + 4*tx] = v;
    }
  }
}

// alpha_src / alpha_dst per node (single head slice)
__global__ void k_al1(const float* __restrict__ hp, const float* __restrict__ asrc,
                      const float* __restrict__ adst,
                      float* __restrict__ als, float* __restrict__ ald){
  int n = blockIdx.x*256 + threadIdx.x;
  if(n >= N_NODES) return;
  const float* row = hp + (size_t)n*64;
  float ss=0.f, sd=0.f;
  #pragma unroll 8
  for(int d=0;d<64;d++){ float v=row[d]; ss += v*asrc[d]; sd += v*adst[d]; }
  als[n]=ss; ald[n]=sd;
}

// ---------------- GAT aggregate (single head, softmax over incoming + self loop) ----------------
__global__ __launch_bounds__(64) void k_gat_agg1(
    const int* __restrict__ rp, const int* __restrict__ col_src, const int* __restrict__ eidA,
    const void* __restrict__ ea, const int* __restrict__ mode,
    const float* __restrict__ hp,
    const float* __restrict__ als, const float* __restrict__ ald,
    const float* __restrict__ loop_attr, const float* __restrict__ we8,
    const float* __restrict__ bias64, float* __restrict__ out, int ldc, int coff){
  int n = blockIdx.x; int t = threadIdx.x;
  __shared__ float sw[64];
  __shared__ int   ssrc[64];
  __shared__ float sE, sSelf;
  int am = *mode;
  int s0 = rp[n], e0 = rp[n+1];
  if((unsigned)s0 > N_EDGES){ s0=0; e0=0; }
  if(e0 < s0 || (unsigned)e0 > N_EDGES) e0 = s0;
  float aldn = ald[n];
  if(t == 0){
    float dot = 0.f;
    #pragma unroll
    for(int k=0;k<8;k++) dot += loop_attr[n*8+k]*we8[k];
    float sc = als[n] + aldn + dot;
    sc = sc > 0.f ? sc : NEG_SLOPE*sc;
    sc = fminf(sc, 30.f);
    float w = expf(sc);
    sSelf = w; sE = w;
  }
  __syncthreads();
  float acc = sSelf * hp[(size_t)n*64 + t];
  for(int base = s0; base < e0; base += 64){
    int m = min(64, e0 - base);
    if(t < m){
      int sn  = col_src[base+t]; if((unsigned)sn  >= N_NODES) sn  = 0;
      int eid = eidA[base+t];    if((unsigned)eid >= N_EDGES) eid = 0;
      float dot = 0.f;
      #pragma unroll
      for(int k=0;k<8;k++) dot += ldF(ea, (size_t)eid*8 + k, am) * we8[k];
      float sc = als[sn] + aldn + dot;
      sc = sc > 0.f ? sc : NEG_SLOPE*sc;
      sc = fminf(sc, 30.f);
      float w = expf(sc);
      sw[t] = w; ssrc[t] = sn;
      atomicAdd(&sE, w);
    }
    __syncthreads();
    for(int i=0;i<m;i++) acc += sw[i] * hp[(size_t)ssrc[i]*64 + t];
    __syncthreads();
  }
  out[(size_t)n*ldc + coff + t] = acc / sE + bias64[t];
}

// ---------------- GCN aggregate ----------------
__global__ __launch_bounds__(64) void k_gcn_agg(
    const int* __restrict__ rp, const int* __restrict__ col_src,
    const float* __restrict__ dinv, const float* __restrict__ gp,
    const float* __restrict__ bias, float* __restrict__ out){
  int n = blockIdx.x; int t = threadIdx.x;
  __shared__ float sw[64];
  __shared__ int   ssrc[64];
  int s0 = rp[n], e0 = rp[n+1];
  if((unsigned)s0 > N_EDGES){ s0=0; e0=0; }
  if(e0 < s0 || (unsigned)e0 > N_EDGES) e0 = s0;
  float dn = dinv[n];
  float acc = dn * gp[(size_t)n*64 + t];
  for(int base = s0; base < e0; base += 64){
    int m = min(64, e0 - base);
    if(t < m){
      int sn = col_src[base+t]; if((unsigned)sn >= N_NODES) sn = 0;
      ssrc[t]=sn; sw[t]=dinv[sn];
    }
    __syncthreads();
    for(int i=0;i<m;i++) acc += sw[i] * gp[(size_t)ssrc[i]*64 + t];
    __syncthreads();
  }
  out[(size_t)n*64 + t] = dn*acc + bias[t];
}

// ---------------- BN stats + apply (f32 data, sanitized) ----------------
template<int C>
__global__ void k_colstats(const float* __restrict__ X, float* __restrict__ sums){
  constexpr int RPB = 128;
  constexpr int RSTEP = 256 / C;
  int c = threadIdx.x % C;
  int r0 = threadIdx.x / C;
  int rbeg = blockIdx.x * RPB;
  int rend = min(N_NODES, rbeg + RPB);
  float s = 0.f, q = 0.f;
  for(int r = rbeg + r0; r < rend; r += RSTEP){
    float v = sane(X[(size_t)r*C + c]);
    s += v; q += v*v;
  }
  atomicAdd(&sums[c], s);
  atomicAdd(&sums[C + c], q);
}

template<int C>
__global__ void k_bn_relu(float* __restrict__ X, const float* __restrict__ sums,
                          const float* __restrict__ g, const float* __restrict__ b){
  int idx = blockIdx.x*256 + threadIdx.x;
  if(idx >= N_NODES*C) return;
  int c = idx % C;
  const float invN = 1.0f / (float)N_NODES;
  float mean = sums[c]*invN;
  float var = fmaxf(sums[C+c]*invN - mean*mean, 0.f);
  float y = (sane(X[idx])-mean)*rsqrtf(var + BN_EPS)*g[c] + b[c];
  X[idx] = fmaxf(y, 0.f);
}

// ---------------- mean pool ----------------
__global__ void k_pool(const float* __restrict__ h, const int* __restrict__ batch,
                       float* __restrict__ psum, float* __restrict__ pcnt){
  int idx = blockIdx.x*256 + threadIdx.x;
  if(idx >= N_NODES*64) return;
  int n = idx >> 6, c = idx & 63;
  int g = batch[n]; if((unsigned)g >= N_GRAPHS) g = 0;
  atomicAdd(&psum[g*64 + c], h[idx]);
  if(c == 0) atomicAdd(&pcnt[g], 1.f);
}

// ---------------- head MLPs + output writeback (mode-aware store) ----------------
__device__ __forceinline__ void stO(void* o, size_t i, float v, int m){
  if(m) ((float*)o)[i] = v; else ((bf16*)o)[i] = f2b(v);
}

__global__ __launch_bounds__(128) void k_head(
    const float* __restrict__ psum, const float* __restrict__ pcnt,
    const float* __restrict__ exf,
    const float* __restrict__ Wex1, const float* __restrict__ bex1,
    const float* __restrict__ Wex2, const float* __restrict__ bex2,
    const float* __restrict__ Wc1, const float* __restrict__ bc1,
    const float* __restrict__ Wc2, const float* __restrict__ bc2,
    const int* __restrict__ mode, void* __restrict__ dout){
  int g = blockIdx.x; int t = threadIdx.x;
  int m0 = *mode;
  __shared__ float ci[128];
  __shared__ float e1[64];
  __shared__ float comb[128];
  __shared__ float red[128];
  if(t < 64){
    float c = fmaxf(pcnt[g], 1.f);
    float xp = sane(psum[g*64 + t]) / c;
    ci[t] = xp;
    stO(dout, 256 + (size_t)g*64 + t, xp, m0);
  } else {
    int j = t - 64;
    float s = bex1[j];
    for(int k=0;k<32;k++) s += exf[g*32 + k] * Wex1[k*64 + j];
    e1[j] = fmaxf(s, 0.f);
  }
  __syncthreads();
  if(t >= 64){
    int j = t - 64;
    float s = bex2[j];
    for(int k=0;k<64;k++) s += e1[k] * Wex2[k*64 + j];
    ci[64 + j] = fmaxf(s, 0.f);
  }
  __syncthreads();
  {
    float s = bc1[t];
    for(int k=0;k<128;k++) s += ci[k] * Wc1[k*128 + t];
    s = fmaxf(s, 0.f);
    comb[t] = s;
    stO(dout, 256 + 16384 + (size_t)g*128 + t, s, m0);
  }
  __syncthreads();
  red[t] = comb[t] * Wc2[t];
  __syncthreads();
  for(int o=64;o>0;o>>=1){ if(t<o) red[t]+=red[t+o]; __syncthreads(); }
  if(t==0) stO(dout, g, red[0] + bc2[0], m0);
}

// ---------------- launch ----------------
extern "C" void kernel_launch(void* const* d_in, const int* in_sizes, int n_in,
                              void* d_out, int out_size, void* d_ws, size_t ws_size,
                              hipStream_t stream){
  const void* x    = d_in[0];
  const void* ea   = d_in[1];
  const int* ei    = (const int*)d_in[3];
  const int* batch = (const int*)d_in[4];
  const int* src = ei;
  const int* dst = ei + N_EDGES;

  char* base = (char*)d_ws;
  size_t off = 0;
  auto alloc = [&](size_t bytes) -> void* {
    void* r = base + off;
    off += (bytes + 255) & ~(size_t)255;
    return r;
  };
  // zero-init region first (one memset)
  int*   cnt    = (int*)  alloc((size_t)N_NODES*4);
  int*   fill   = (int*)  alloc((size_t)N_NODES*4);
  float* bnstat = (float*)alloc(4096);
  float* pool   = (float*)alloc((size_t)(N_GRAPHS*64 + N_GRAPHS)*4);
  size_t zbytes = off;
  int*   rp      = (int*)  alloc((size_t)(N_NODES+1)*4);
  int*   bsum    = (int*)  alloc(256*4);
  int*   bofs    = (int*)  alloc(256*4);
  int*   col_src = (int*)  alloc((size_t)N_EDGES*4);
  int*   eidA    = (int*)  alloc((size_t)N_EDGES*4);
  float* loop_attr=(float*)alloc((size_t)N_NODES*8*4);
  float* dinv    = (float*)alloc((size_t)N_NODES*4);
  float* w_e     = (float*)alloc(64*4);
  float* als     = (float*)alloc((size_t)N_NODES*4);
  float* ald     = (float*)alloc((size_t)N_NODES*4);
  int*   mode    = (int*)  alloc(8);          // [0]=detected, [1]=1 (f32 const)
  float* wbank   = (float*)alloc(80000*4);
  float* hp      = (float*)alloc((size_t)N_NODES*64*4);
  float* out1    = (float*)alloc((size_t)N_NODES*256*4);
  // ~80 MB total

  float* out2 = out1;                         // aliases (out1 dead when written)
  float* out3 = out1 + (size_t)N_NODES*64;
  float* out4 = out1 + (size_t)N_NODES*128;
  float* bn1 = bnstat;
  float* bn2 = bnstat + 512;
  float* bn3 = bnstat + 640;
  float* bn4 = bnstat + 768;
  float* psum = pool;
  float* pcnt = pool + N_GRAPHS*64;
  int* fone = mode + 1;

  // ---- weight bank ----
  const int segidx[NSEG] = {2, 5,6,7,8,9,10,11,12, 13,14,15,16,17,18,19,20,
                            21,22,23,24, 25,26,27,28, 29,30,31,32, 33,34,35,36};
  const int segn[NSEG] = {8192, 16384,256,256,2048,256,256,256,256,
                          16384,64,64,512,64,64,64,64,
                          4096,64,64,64, 4096,64,64,64,
                          2048,64,4096,64, 16384,128,128,1};
  Bank bk;
  int offs[NSEG]; int acc0 = 0;
  for(int i=0;i<NSEG;i++){ bk.p[i]=d_in[segidx[i]]; bk.n[i]=segn[i]; bk.off[i]=acc0; offs[i]=acc0; acc0+=segn[i]; }
  const float* f_exf = wbank + offs[0];
  const float* fW1 = wbank+offs[1]; const float* fas1 = wbank+offs[2]; const float* fad1 = wbank+offs[3];
  const float* fWe1= wbank+offs[4]; const float* fae1 = wbank+offs[5]; const float* fb1  = wbank+offs[6];
  const float* fg1 = wbank+offs[7]; const float* fbe1 = wbank+offs[8];
  const float* fW2 = wbank+offs[9]; const float* fas2 = wbank+offs[10]; const float* fad2 = wbank+offs[11];
  const float* fWe2= wbank+offs[12]; const float* fae2 = wbank+offs[13]; const float* fb2 = wbank+offs[14];
  const float* fg2 = wbank+offs[15]; const float* fbe2 = wbank+offs[16];
  const float* fWg1= wbank+offs[17]; const float* fbg1 = wbank+offs[18]; const float* fg3 = wbank+offs[19];
  const float* fbe3= wbank+offs[20];
  const float* fWg2= wbank+offs[21]; const float* fbg2 = wbank+offs[22]; const float* fg4 = wbank+offs[23];
  const float* fbe4= wbank+offs[24];
  const float* fWex1=wbank+offs[25]; const float* fbex1= wbank+offs[26];
  const float* fWex2=wbank+offs[27]; const float* fbex2= wbank+offs[28];
  const float* fWc1= wbank+offs[29]; const float* fbc1 = wbank+offs[30];
  const float* fWc2= wbank+offs[31]; const float* fbc2 = wbank+offs[32];

  const int nbN  = (N_NODES + 255)/256;
  const int nbE  = (N_EDGES + 255)/256;
  const int nb64 = (N_NODES*64 + 255)/256;
  const int nbT  = (N_NODES + 63)/64;        // 782 GEMM row-tiles

  hipMemsetAsync(d_ws, 0, zbytes, stream);
  k_detect<<<1,64,0,stream>>>(x, mode);
  {
    dim3 g((16384+255)/256, NSEG);
    k_convert<<<g,256,0,stream>>>(bk, mode, wbank);
  }
  k_count<<<nbE,256,0,stream>>>(dst, cnt);
  k_blocksum<<<nbN,256,0,stream>>>(cnt, bsum);
  k_scan_bsum<<<1,256,0,stream>>>(bsum, bofs, nbN);
  k_scan_write<<<nbN,256,0,stream>>>(cnt, bofs, rp);
  k_fill<<<nbE,256,0,stream>>>(src, dst, rp, fill, col_src, eidA);
  k_node_misc<<<nbN,256,0,stream>>>(rp, eidA, ea, mode, loop_attr, dinv);
  k_we<<<1,64,0,stream>>>(fWe1, fae1, fWe2, fae2, w_e);

  // GAT layer 1 (4 heads sequentially, concat -> out1 [N,256])
  for(int h=0; h<4; h++){
    k_gemm_t<64><<<nbT,256,0,stream>>>(x, 64, mode, fW1, 256, h*64, hp, 64, 0, N_NODES);
    k_al1<<<nbN,256,0,stream>>>(hp, fas1 + h*64, fad1 + h*64, als, ald);
    k_gat_agg1<<<N_NODES,64,0,stream>>>(rp, col_src, eidA, ea, mode, hp,
                                        als, ald, loop_attr, w_e + h*8,
                                        fb1 + h*64, out1, 256, h*64);
  }
  k_colstats<256><<<(N_NODES+127)/128,256,0,stream>>>(out1, bn1);
  k_bn_relu<256><<<(N_NODES*256+255)/256,256,0,stream>>>(out1, bn1, fg1, fbe1);

  // GAT layer 2 (1 head, mean==identity -> out2 [N,64])
  k_gemm_t<256><<<nbT,256,0,stream>>>(out1, 256, fone, fW2, 64, 0, hp, 64, 0, N_NODES);
  k_al1<<<nbN,256,0,stream>>>(hp, fas2, fad2, als, ald);
  k_gat_agg1<<<N_NODES,64,0,stream>>>(rp, col_src, eidA, ea, mode, hp,
                                      als, ald, loop_attr, w_e + 32, fb2, out2, 64, 0);
  k_colstats<64><<<(N_NODES+127)/128,256,0,stream>>>(out2, bn2);
  k_bn_relu<64><<<nb64,256,0,stream>>>(out2, bn2, fg2, fbe2);

  // GCN layer 1
  k_gemm_t<64><<<nbT,256,0,stream>>>(out2, 64, fone, fWg1, 64, 0, hp, 64, 0, N_NODES);
  k_gcn_agg<<<N_NODES,64,0,stream>>>(rp, col_src, dinv, hp, fbg1, out3);
  k_colstats<64><<<(N_NODES+127)/128,256,0,stream>>>(out3, bn3);
  k_bn_relu<64><<<nb64,256,0,stream>>>(out3, bn3, fg3, fbe3);

  // GCN layer 2
  k_gemm_t<64><<<nbT,256,0,stream>>>(out3, 64, fone, fWg2, 64, 0, hp, 64, 0, N_NODES);
  k_gcn_agg<<<N_NODES,64,0,stream>>>(rp, col_src, dinv, hp, fbg2, out4);
  k_colstats<64><<<(N_NODES+127)/128,256,0,stream>>>(out4, bn4);
  k_bn_relu<64><<<nb64,256,0,stream>>>(out4, bn4, fg4, fbe4);

  // pool + head
  k_pool<<<nb64,256,0,stream>>>(out4, batch, psum, pcnt);
  k_head<<<N_GRAPHS,128,0,stream>>>(psum, pcnt, f_exf, fWex1, fbex1, fWex2, fbex2,
                                    fWc1, fbc1, fWc2, fbc2, mode, d_out);
}

// Round 5
// 1377.566 us; speedup vs baseline: 1.3684x; 1.2053x over previous
//
#include <hip/hip_runtime.h>
#include <hip/hip_bf16.h>

#define N_NODES 50000
#define N_EDGES 1600000
#define N_GRAPHS 256
#define NEG_SLOPE 0.2f
#define BN_EPS 1e-5f

typedef __hip_bfloat16 bf16;

__device__ __forceinline__ float b2f(bf16 v){ return __bfloat162float(v); }
__device__ __forceinline__ bf16 f2b(float v){ return __float2bfloat16(v); }
__device__ __forceinline__ float us2f(unsigned short u){ return __uint_as_float(((unsigned)u)<<16); }
__device__ __forceinline__ unsigned short f2us(float v){ bf16 b = f2b(v); return *(unsigned short*)&b; }
// mode: 1 => external float tensors are f32, 0 => bf16
__device__ __forceinline__ float ldF(const void* p, size_t i, int m){
  return m ? ((const float*)p)[i] : b2f(((const bf16*)p)[i]);
}
__device__ __forceinline__ float sane(float v){
  return (v == v && fabsf(v) < 1e30f) ? v : 0.f;
}

// ---------------- dtype detection ----------------
__global__ void k_detect(const void* x, int* flag){
  if(threadIdx.x == 0 && blockIdx.x == 0){
    const unsigned short* u = (const unsigned short*)x;
    int insane = 0;
    for(int i=0;i<1024;i++){
      float v = fabsf(us2f(u[i]));
      if(!(v > 1e-6f && v < 1e4f)) insane++;
    }
    flag[0] = (insane > 128) ? 1 : 0;  // 1 => data is f32
    flag[1] = 1;                       // constant "f32" flag
  }
}

// ---------------- weight bank conversion ----------------
#define NSEG 33
struct Bank { const void* p[NSEG]; int n[NSEG]; int off[NSEG]; };

__global__ void k_convert(Bank b, const int* mode, float* out){
  int seg = blockIdx.y;
  int i = blockIdx.x*256 + threadIdx.x;
  int m = *mode;
  if(i < b.n[seg]) out[b.off[seg] + i] = ldF(b.p[seg], i, m);
}

// w_e[h][k] = sum_d We[k, h*64+d] * a_e[h, d]  (layer1 heads 0..3 -> w_e[0..31], layer2 -> w_e[32..39])
__global__ void k_we(const float* __restrict__ We1, const float* __restrict__ ae1,
                     const float* __restrict__ We2, const float* __restrict__ ae2,
                     float* __restrict__ w_e){
  int t = threadIdx.x;
  if(t < 32){
    int h = t >> 3, k = t & 7;
    float s = 0.f;
    for(int d=0;d<64;d++) s += We1[k*256 + h*64 + d] * ae1[h*64 + d];
    w_e[t] = s;
  } else if(t < 40){
    int k = t - 32;
    float s = 0.f;
    for(int d=0;d<64;d++) s += We2[k*64 + d] * ae2[d];
    w_e[t] = s;
  }
}

// ---------------- CSR build ----------------
__global__ void k_count(const int* __restrict__ dst, int* __restrict__ cnt){
  int e = blockIdx.x*256 + threadIdx.x;
  if(e < N_EDGES){
    int d = dst[e]; if((unsigned)d >= N_NODES) d = 0;
    atomicAdd(&cnt[d], 1);
  }
}

__global__ void k_blocksum(const int* __restrict__ cnt, int* __restrict__ bsum){
  __shared__ int s[256];
  int i = blockIdx.x*256 + threadIdx.x;
  s[threadIdx.x] = (i < N_NODES) ? cnt[i] : 0;
  __syncthreads();
  for(int o=128;o>0;o>>=1){ if(threadIdx.x<o) s[threadIdx.x]+=s[threadIdx.x+o]; __syncthreads(); }
  if(threadIdx.x==0) bsum[blockIdx.x]=s[0];
}

__global__ void k_scan_bsum(const int* __restrict__ bsum, int* __restrict__ bofs, int nb){
  __shared__ int s[256];
  int t = threadIdx.x;
  s[t] = (t<nb) ? bsum[t] : 0;
  __syncthreads();
  for(int o=1;o<256;o<<=1){ int v=(t>=o)?s[t-o]:0; __syncthreads(); s[t]+=v; __syncthreads(); }
  bofs[t] = (t==0) ? 0 : s[t-1];
}

__global__ void k_scan_write(const int* __restrict__ cnt, const int* __restrict__ bofs, int* __restrict__ rp){
  __shared__ int s[256];
  int t = threadIdx.x; int i = blockIdx.x*256 + t;
  int v = (i<N_NODES) ? cnt[i] : 0;
  s[t]=v; __syncthreads();
  for(int o=1;o<256;o<<=1){ int a=(t>=o)?s[t-o]:0; __syncthreads(); s[t]+=a; __syncthreads(); }
  if(i<N_NODES) rp[i+1] = s[t] + bofs[blockIdx.x];
  if(i==0) rp[0]=0;
}

// fill CSR + per-edge attention dot-products (bf16, CSR slot order)
__global__ void k_fill(const int* __restrict__ src, const int* __restrict__ dst,
                       const int* __restrict__ rp, int* __restrict__ fill,
                       const void* __restrict__ ea, const int* __restrict__ mode,
                       const float* __restrict__ w_e,
                       int* __restrict__ col_src,
                       unsigned short* __restrict__ edot4, unsigned short* __restrict__ edot1){
  int e = blockIdx.x*256 + threadIdx.x;
  if(e >= N_EDGES) return;
  int d = dst[e]; if((unsigned)d >= N_NODES) d = 0;
  int p = atomicAdd(&fill[d], 1);
  int slot = rp[d] + p;
  if((unsigned)slot >= N_EDGES) return;
  int sv = src[e]; if((unsigned)sv >= N_NODES) sv = 0;
  col_src[slot] = sv;
  int m = *mode;
  float a[8];
  #pragma unroll
  for(int k=0;k<8;k++) a[k] = ldF(ea, (size_t)e*8 + k, m);
  unsigned short d4[4];
  #pragma unroll
  for(int h=0;h<4;h++){
    float s = 0.f;
    #pragma unroll
    for(int k=0;k<8;k++) s += a[k]*w_e[h*8+k];
    d4[h] = f2us(s);
  }
  *(ushort4*)&edot4[(size_t)slot*4] = make_ushort4(d4[0],d4[1],d4[2],d4[3]);
  float s1 = 0.f;
  #pragma unroll
  for(int k=0;k<8;k++) s1 += a[k]*w_e[32+k];
  edot1[slot] = f2us(s1);
}

__global__ void k_dinv(const int* __restrict__ rp, float* __restrict__ dinv){
  int n = blockIdx.x*256 + threadIdx.x;
  if(n >= N_NODES) return;
  int s = rp[n], e = rp[n+1];
  int deg = (e >= s) ? (e - s) : 0;
  dinv[n] = rsqrtf((float)deg + 1.f);
}

// ---------------- tiled GEMM: C[:, coff..] = A[:,:KIN] @ W[:, woff..], 64x64 tiles, bf16 or f32 out ----
template<int KIN, bool OUTBF>
__global__ __launch_bounds__(256) void k_gemm_t(
    const void* __restrict__ A, int lda, const int* __restrict__ amode,
    const float* __restrict__ W, int ldw, int woffB,
    void* __restrict__ C, int ldc, int coffB, int M)
{
  __shared__ float As[64][68];
  __shared__ float Ws[64][64];
  const int tid = threadIdx.x;
  const int bm  = blockIdx.x * 64;
  const int woff = woffB + blockIdx.y * 64;
  const int coff = coffB + blockIdx.y * 64;
  const int tx  = tid & 15;
  const int ty  = tid >> 4;
  const int am  = *amode;
  float acc[4][4] = {};

  for(int k0 = 0; k0 < KIN; k0 += 64){
    if(am){
      const float* Af = (const float*)A;
      #pragma unroll
      for(int f = tid; f < 1024; f += 256){
        int r = f >> 4, kq = f & 15;
        int row = bm + r;
        float4 v = make_float4(0.f,0.f,0.f,0.f);
        if(row < M) v = *(const float4*)&Af[(size_t)row*lda + k0 + 4*kq];
        *(float4*)&As[r][4*kq] = v;
      }
    } else {
      const bf16* Ab = (const bf16*)A;
      #pragma unroll
      for(int f = tid; f < 1024; f += 256){
        int r = f >> 4, kq = f & 15;
        int row = bm + r;
        float4 v = make_float4(0.f,0.f,0.f,0.f);
        if(row < M){
          const bf16* p = &Ab[(size_t)row*lda + k0 + 4*kq];
          v = make_float4(b2f(p[0]), b2f(p[1]), b2f(p[2]), b2f(p[3]));
        }
        *(float4*)&As[r][4*kq] = v;
      }
    }
    #pragma unroll
    for(int g = tid; g < 1024; g += 256){
      int kr = g >> 4, jq = g & 15;
      *(float4*)&Ws[kr][4*jq] = *(const float4*)&W[(size_t)(k0+kr)*ldw + woff + 4*jq];
    }
    __syncthreads();
    #pragma unroll
    for(int k = 0; k < 64; k += 4){
      float4 av[4], wv[4];
      #pragma unroll
      for(int r=0;r<4;r++) av[r] = *(const float4*)&As[4*ty + r][k];
      #pragma unroll
      for(int kk=0;kk<4;kk++) wv[kk] = *(const float4*)&Ws[k + kk][4*tx];
      #pragma unroll
      for(int r=0;r<4;r++){
        const float a0=av[r].x, a1=av[r].y, a2=av[r].z, a3=av[r].w;
        acc[r][0] += a0*wv[0].x + a1*wv[1].x + a2*wv[2].x + a3*wv[3].x;
        acc[r][1] += a0*wv[0].y + a1*wv[1].y + a2*wv[2].y + a3*wv[3].y;
        acc[r][2] += a0*wv[0].z + a1*wv[1].z + a2*wv[2].z + a3*wv[3].z;
        acc[r][3] += a0*wv[0].w + a1*wv[1].w + a2*wv[2].w + a3*wv[3].w;
      }
    }
    __syncthreads();
  }
  #pragma unroll
  for(int r=0;r<4;r++){
    int row = bm + 4*ty + r;
    if(row < M){
      if(OUTBF){
        bf16* Cb = (bf16*)C;
        ushort4 u = make_ushort4(f2us(acc[r][0]), f2us(acc[r][1]), f2us(acc[r][2]), f2us(acc[r][3]));
        *(ushort4*)&Cb[(size_t)row*ldc + coff + 4*tx] = u;
      } else {
        float* Cf = (float*)C;
        *(float4*)&Cf[(size_t)row*ldc + coff + 4*tx] =
            make_float4(acc[r][0], acc[r][1], acc[r][2], acc[r][3]);
      }
    }
  }
}

// ---------------- alpha dots ----------------
// 4-head: hp [N,256] bf16, als4/ald4 [N][4]
__global__ void k_al4(const bf16* __restrict__ hp, const float* __restrict__ asrc,
                      const float* __restrict__ adst,
                      float* __restrict__ als4, float* __restrict__ ald4){
  int idx = blockIdx.x*256 + threadIdx.x;
  if(idx >= N_NODES*4) return;
  int n = idx >> 2, h = idx & 3;
  const bf16* row = hp + (size_t)n*256 + h*64;
  float ss=0.f, sd=0.f;
  #pragma unroll 8
  for(int d=0;d<64;d++){ float v=b2f(row[d]); ss += v*asrc[h*64+d]; sd += v*adst[h*64+d]; }
  als4[idx]=ss; ald4[idx]=sd;
}

// 1-head: hp [N,64] bf16
__global__ void k_al1(const bf16* __restrict__ hp, const float* __restrict__ asrc,
                      const float* __restrict__ adst,
                      float* __restrict__ als, float* __restrict__ ald){
  int n = blockIdx.x*256 + threadIdx.x;
  if(n >= N_NODES) return;
  const bf16* row = hp + (size_t)n*64;
  float ss=0.f, sd=0.f;
  #pragma unroll 8
  for(int d=0;d<64;d++){ float v=b2f(row[d]); ss += v*asrc[d]; sd += v*adst[d]; }
  als[n]=ss; ald[n]=sd;
}

// ---------------- fused 4-head GAT aggregate ----------------
__global__ __launch_bounds__(256) void k_gat_agg4(
    const int* __restrict__ rp, const int* __restrict__ col_src,
    const unsigned short* __restrict__ edot4,
    const bf16* __restrict__ hp,                 // [N,256]
    const float* __restrict__ als4, const float* __restrict__ ald4,
    const float* __restrict__ bias256, float* __restrict__ out1){
  int n = blockIdx.x; int t = threadIdx.x;
  int head = t >> 6;          // output role
  int eL = t >> 2, hL = t & 3; // scoring role
  __shared__ float sw[64][4];
  __shared__ int   ssrc[64];
  __shared__ float swsum[256];
  __shared__ float sdsum[256];
  int s0 = rp[n], e0 = rp[n+1];
  if((unsigned)s0 > N_EDGES){ s0=0; e0=0; }
  if(e0 < s0 || (unsigned)e0 > N_EDGES) e0 = s0;
  float aldL = ald4[n*4 + hL];
  float wsum_l = 0.f, dsum_l = 0.f, acc = 0.f;
  const unsigned short* hpu = (const unsigned short*)hp;
  for(int base = s0; base < e0; base += 64){
    int m = min(64, e0 - base);
    if(eL < m){
      int sn = col_src[base+eL]; if((unsigned)sn >= N_NODES) sn = 0;
      if(hL == 0) ssrc[eL] = sn;
      float ed = us2f(edot4[(size_t)(base+eL)*4 + hL]);
      float sc = als4[sn*4 + hL] + aldL + ed;
      sc = sc > 0.f ? sc : NEG_SLOPE*sc;
      sc = fminf(sc, 30.f);
      float w = expf(sc);
      sw[eL][hL] = w;
      wsum_l += w; dsum_l += ed;
    }
    __syncthreads();
    for(int i=0;i<m;i++)
      acc += sw[i][head] * us2f(hpu[(size_t)ssrc[i]*256 + t]);
    __syncthreads();
  }
  swsum[t] = wsum_l; sdsum[t] = dsum_l;
  __syncthreads();
  float sE = 0.f, sD = 0.f;
  for(int i=0;i<64;i++){ sE += swsum[4*i + head]; sD += sdsum[4*i + head]; }
  float deg = (float)(e0 - s0);
  float sdot = deg > 0.f ? sD/deg : 0.f;
  float sc = als4[n*4 + head] + ald4[n*4 + head] + sdot;
  sc = sc > 0.f ? sc : NEG_SLOPE*sc;
  sc = fminf(sc, 30.f);
  float w = expf(sc);
  float self = us2f(hpu[(size_t)n*256 + t]);
  out1[(size_t)n*256 + t] = (acc + w*self)/(sE + w) + bias256[t];
}

// ---------------- single-head GAT aggregate (layer 2) ----------------
__global__ __launch_bounds__(64) void k_gat_agg1e(
    const int* __restrict__ rp, const int* __restrict__ col_src,
    const unsigned short* __restrict__ edot1,
    const bf16* __restrict__ hp,                 // [N,64]
    const float* __restrict__ als, const float* __restrict__ ald,
    const float* __restrict__ bias64, float* __restrict__ out){
  int n = blockIdx.x; int t = threadIdx.x;
  __shared__ float sw[64];
  __shared__ int   ssrc[64];
  __shared__ float swsum[64];
  __shared__ float sdsum[64];
  int s0 = rp[n], e0 = rp[n+1];
  if((unsigned)s0 > N_EDGES){ s0=0; e0=0; }
  if(e0 < s0 || (unsigned)e0 > N_EDGES) e0 = s0;
  float aldn = ald[n];
  float wsum_l = 0.f, dsum_l = 0.f, acc = 0.f;
  const unsigned short* hpu = (const unsigned short*)hp;
  for(int base = s0; base < e0; base += 64){
    int m = min(64, e0 - base);
    if(t < m){
      int sn = col_src[base+t]; if((unsigned)sn >= N_NODES) sn = 0;
      ssrc[t] = sn;
      float ed = us2f(edot1[base+t]);
      float sc = als[sn] + aldn + ed;
      sc = sc > 0.f ? sc : NEG_SLOPE*sc;
      sc = fminf(sc, 30.f);
      float w = expf(sc);
      sw[t] = w;
      wsum_l += w; dsum_l += ed;
    }
    __syncthreads();
    for(int i=0;i<m;i++)
      acc += sw[i] * us2f(hpu[(size_t)ssrc[i]*64 + t]);
    __syncthreads();
  }
  swsum[t] = wsum_l; sdsum[t] = dsum_l;
  __syncthreads();
  float sE = 0.f, sD = 0.f;
  for(int i=0;i<64;i++){ sE += swsum[i]; sD += sdsum[i]; }
  float deg = (float)(e0 - s0);
  float sdot = deg > 0.f ? sD/deg : 0.f;
  float sc = als[n] + aldn + sdot;
  sc = sc > 0.f ? sc : NEG_SLOPE*sc;
  sc = fminf(sc, 30.f);
  float w = expf(sc);
  float self = us2f(hpu[(size_t)n*64 + t]);
  out[(size_t)n*64 + t] = (acc + w*self)/(sE + w) + bias64[t];
}

// ---------------- GCN aggregate (bf16 features) ----------------
__global__ __launch_bounds__(64) void k_gcn_agg(
    const int* __restrict__ rp, const int* __restrict__ col_src,
    const float* __restrict__ dinv, const bf16* __restrict__ gp,
    const float* __restrict__ bias, float* __restrict__ out){
  int n = blockIdx.x; int t = threadIdx.x;
  __shared__ float sw[64];
  __shared__ int   ssrc[64];
  int s0 = rp[n], e0 = rp[n+1];
  if((unsigned)s0 > N_EDGES){ s0=0; e0=0; }
  if(e0 < s0 || (unsigned)e0 > N_EDGES) e0 = s0;
  float dn = dinv[n];
  const unsigned short* gpu = (const unsigned short*)gp;
  float acc = dn * us2f(gpu[(size_t)n*64 + t]);
  for(int base = s0; base < e0; base += 64){
    int m = min(64, e0 - base);
    if(t < m){
      int sn = col_src[base+t]; if((unsigned)sn >= N_NODES) sn = 0;
      ssrc[t]=sn; sw[t]=dinv[sn];
    }
    __syncthreads();
    for(int i=0;i<m;i++) acc += sw[i] * us2f(gpu[(size_t)ssrc[i]*64 + t]);
    __syncthreads();
  }
  out[(size_t)n*64 + t] = dn*acc + bias[t];
}

// ---------------- BN stats + apply (f32 data) ----------------
template<int C>
__global__ void k_colstats(const float* __restrict__ X, float* __restrict__ sums){
  constexpr int RPB = 128;
  constexpr int RSTEP = 256 / C;
  int c = threadIdx.x % C;
  int r0 = threadIdx.x / C;
  int rbeg = blockIdx.x * RPB;
  int rend = min(N_NODES, rbeg + RPB);
  float s = 0.f, q = 0.f;
  for(int r = rbeg + r0; r < rend; r += RSTEP){
    float v = sane(X[(size_t)r*C + c]);
    s += v; q += v*v;
  }
  atomicAdd(&sums[c], s);
  atomicAdd(&sums[C + c], q);
}

template<int C>
__global__ void k_bn_relu(float* __restrict__ X, const float* __restrict__ sums,
                          const float* __restrict__ g, const float* __restrict__ b){
  int idx = blockIdx.x*256 + threadIdx.x;
  if(idx >= N_NODES*C) return;
  int c = idx % C;
  const float invN = 1.0f / (float)N_NODES;
  float mean = sums[c]*invN;
  float var = fmaxf(sums[C+c]*invN - mean*mean, 0.f);
  float y = (sane(X[idx])-mean)*rsqrtf(var + BN_EPS)*g[c] + b[c];
  X[idx] = fmaxf(y, 0.f);
}

// ---------------- mean pool (sorted batch, segmented) ----------------
__global__ __launch_bounds__(64) void k_pool2(
    const float* __restrict__ h, const int* __restrict__ batch,
    float* __restrict__ psum, float* __restrict__ pcnt){
  int t = threadIdx.x;
  int n0 = blockIdx.x * 256;
  int n1 = min(N_NODES, n0 + 256);
  if(n0 >= n1) return;
  int cur = batch[n0]; if((unsigned)cur >= N_GRAPHS) cur = 0;
  float acc = 0.f; int cl = 0;
  for(int n = n0; n < n1; n++){
    int g = batch[n]; if((unsigned)g >= N_GRAPHS) g = 0;
    if(g != cur){
      atomicAdd(&psum[cur*64 + t], acc);
      if(t == 0) atomicAdd(&pcnt[cur], (float)cl);
      acc = 0.f; cl = 0; cur = g;
    }
    acc += h[(size_t)n*64 + t];
    cl++;
  }
  atomicAdd(&psum[cur*64 + t], acc);
  if(t == 0) atomicAdd(&pcnt[cur], (float)cl);
}

// ---------------- head MLPs + output writeback (mode-aware store) ----------------
__device__ __forceinline__ void stO(void* o, size_t i, float v, int m){
  if(m) ((float*)o)[i] = v; else ((bf16*)o)[i] = f2b(v);
}

__global__ __launch_bounds__(128) void k_head(
    const float* __restrict__ psum, const float* __restrict__ pcnt,
    const float* __restrict__ exf,
    const float* __restrict__ Wex1, const float* __restrict__ bex1,
    const float* __restrict__ Wex2, const float* __restrict__ bex2,
    const float* __restrict__ Wc1, const float* __restrict__ bc1,
    const float* __restrict__ Wc2, const float* __restrict__ bc2,
    const int* __restrict__ mode, void* __restrict__ dout){
  int g = blockIdx.x; int t = threadIdx.x;
  int m0 = *mode;
  __shared__ float ci[128];
  __shared__ float e1[64];
  __shared__ float comb[128];
  __shared__ float red[128];
  if(t < 64){
    float c = fmaxf(pcnt[g], 1.f);
    float xp = sane(psum[g*64 + t]) / c;
    ci[t] = xp;
    stO(dout, 256 + (size_t)g*64 + t, xp, m0);
  } else {
    int j = t - 64;
    float s = bex1[j];
    for(int k=0;k<32;k++) s += exf[g*32 + k] * Wex1[k*64 + j];
    e1[j] = fmaxf(s, 0.f);
  }
  __syncthreads();
  if(t >= 64){
    int j = t - 64;
    float s = bex2[j];
    for(int k=0;k<64;k++) s += e1[k] * Wex2[k*64 + j];
    ci[64 + j] = fmaxf(s, 0.f);
  }
  __syncthreads();
  {
    float s = bc1[t];
    for(int k=0;k<128;k++) s += ci[k] * Wc1[k*128 + t];
    s = fmaxf(s, 0.f);
    comb[t] = s;
    stO(dout, 256 + 16384 + (size_t)g*128 + t, s, m0);
  }
  __syncthreads();
  red[t] = comb[t] * Wc2[t];
  __syncthreads();
  for(int o=64;o>0;o>>=1){ if(t<o) red[t]+=red[t+o]; __syncthreads(); }
  if(t==0) stO(dout, g, red[0] + bc2[0], m0);
}

// ---------------- launch ----------------
extern "C" void kernel_launch(void* const* d_in, const int* in_sizes, int n_in,
                              void* d_out, int out_size, void* d_ws, size_t ws_size,
                              hipStream_t stream){
  const void* x    = d_in[0];
  const void* ea   = d_in[1];
  const int* ei    = (const int*)d_in[3];
  const int* batch = (const int*)d_in[4];
  const int* src = ei;
  const int* dst = ei + N_EDGES;

  char* base = (char*)d_ws;
  size_t off = 0;
  auto alloc = [&](size_t bytes) -> void* {
    void* r = base + off;
    off += (bytes + 255) & ~(size_t)255;
    return r;
  };
  // zero-init region
  int*   cnt    = (int*)  alloc((size_t)N_NODES*4);
  int*   fill   = (int*)  alloc((size_t)N_NODES*4);
  float* bnstat = (float*)alloc(4096);
  float* pool   = (float*)alloc((size_t)(N_GRAPHS*64 + N_GRAPHS)*4);
  size_t zbytes = off;
  int*   rp      = (int*)  alloc((size_t)(N_NODES+1)*4);
  int*   bsum    = (int*)  alloc(256*4);
  int*   bofs    = (int*)  alloc(256*4);
  int*   col_src = (int*)  alloc((size_t)N_EDGES*4);
  unsigned short* edot4 = (unsigned short*)alloc((size_t)N_EDGES*4*2);  // bf16 x4
  unsigned short* edot1 = (unsigned short*)alloc((size_t)N_EDGES*2);    // bf16
  float* dinv    = (float*)alloc((size_t)N_NODES*4);
  float* w_e     = (float*)alloc(64*4);
  float* als4    = (float*)alloc((size_t)N_NODES*4*4);
  float* ald4    = (float*)alloc((size_t)N_NODES*4*4);
  int*   mode    = (int*)  alloc(8);
  float* wbank   = (float*)alloc(80000*4);
  bf16*  hp      = (bf16*) alloc((size_t)N_NODES*256*2);   // projected feats (bf16)
  float* out1    = (float*)alloc((size_t)N_NODES*256*4);   // f32
  // ~102 MB total

  float* out2 = out1;                          // aliases within out1 (dead regions)
  float* out3 = out1 + (size_t)N_NODES*64;
  float* out4 = out1 + (size_t)N_NODES*128;
  float* bn1 = bnstat;
  float* bn2 = bnstat + 512;
  float* bn3 = bnstat + 640;
  float* bn4 = bnstat + 768;
  float* psum = pool;
  float* pcnt = pool + N_GRAPHS*64;
  int* fone = mode + 1;

  // ---- weight bank ----
  const int segidx[NSEG] = {2, 5,6,7,8,9,10,11,12, 13,14,15,16,17,18,19,20,
                            21,22,23,24, 25,26,27,28, 29,30,31,32, 33,34,35,36};
  const int segn[NSEG] = {8192, 16384,256,256,2048,256,256,256,256,
                          16384,64,64,512,64,64,64,64,
                          4096,64,64,64, 4096,64,64,64,
                          2048,64,4096,64, 16384,128,128,1};
  Bank bk;
  int offs[NSEG]; int acc0 = 0;
  for(int i=0;i<NSEG;i++){ bk.p[i]=d_in[segidx[i]]; bk.n[i]=segn[i]; bk.off[i]=acc0; offs[i]=acc0; acc0+=segn[i]; }
  const float* f_exf = wbank + offs[0];
  const float* fW1 = wbank+offs[1]; const float* fas1 = wbank+offs[2]; const float* fad1 = wbank+offs[3];
  const float* fWe1= wbank+offs[4]; const float* fae1 = wbank+offs[5]; const float* fb1  = wbank+offs[6];
  const float* fg1 = wbank+offs[7]; const float* fbe1 = wbank+offs[8];
  const float* fW2 = wbank+offs[9]; const float* fas2 = wbank+offs[10]; const float* fad2 = wbank+offs[11];
  const float* fWe2= wbank+offs[12]; const float* fae2 = wbank+offs[13]; const float* fb2 = wbank+offs[14];
  const float* fg2 = wbank+offs[15]; const float* fbe2 = wbank+offs[16];
  const float* fWg1= wbank+offs[17]; const float* fbg1 = wbank+offs[18]; const float* fg3 = wbank+offs[19];
  const float* fbe3= wbank+offs[20];
  const float* fWg2= wbank+offs[21]; const float* fbg2 = wbank+offs[22]; const float* fg4 = wbank+offs[23];
  const float* fbe4= wbank+offs[24];
  const float* fWex1=wbank+offs[25]; const float* fbex1= wbank+offs[26];
  const float* fWex2=wbank+offs[27]; const float* fbex2= wbank+offs[28];
  const float* fWc1= wbank+offs[29]; const float* fbc1 = wbank+offs[30];
  const float* fWc2= wbank+offs[31]; const float* fbc2 = wbank+offs[32];

  const int nbN  = (N_NODES + 255)/256;
  const int nbE  = (N_EDGES + 255)/256;
  const int nb64 = (N_NODES*64 + 255)/256;
  const int nbT  = (N_NODES + 63)/64;

  hipMemsetAsync(d_ws, 0, zbytes, stream);
  k_detect<<<1,64,0,stream>>>(x, mode);
  {
    dim3 g((16384+255)/256, NSEG);
    k_convert<<<g,256,0,stream>>>(bk, mode, wbank);
  }
  k_we<<<1,64,0,stream>>>(fWe1, fae1, fWe2, fae2, w_e);
  k_count<<<nbE,256,0,stream>>>(dst, cnt);
  k_blocksum<<<nbN,256,0,stream>>>(cnt, bsum);
  k_scan_bsum<<<1,256,0,stream>>>(bsum, bofs, nbN);
  k_scan_write<<<nbN,256,0,stream>>>(cnt, bofs, rp);
  k_fill<<<nbE,256,0,stream>>>(src, dst, rp, fill, ea, mode, w_e, col_src, edot4, edot1);
  k_dinv<<<nbN,256,0,stream>>>(rp, dinv);

  // GAT layer 1 (4 heads fused)
  {
    dim3 g(nbT, 4);
    k_gemm_t<64,true><<<g,256,0,stream>>>(x, 64, mode, fW1, 256, 0, hp, 256, 0, N_NODES);
  }
  k_al4<<<(N_NODES*4+255)/256,256,0,stream>>>(hp, fas1, fad1, als4, ald4);
  k_gat_agg4<<<N_NODES,256,0,stream>>>(rp, col_src, edot4, hp, als4, ald4, fb1, out1);
  k_colstats<256><<<(N_NODES+127)/128,256,0,stream>>>(out1, bn1);
  k_bn_relu<256><<<(N_NODES*256+255)/256,256,0,stream>>>(out1, bn1, fg1, fbe1);

  // GAT layer 2 (1 head)
  k_gemm_t<256,true><<<nbT,256,0,stream>>>(out1, 256, fone, fW2, 64, 0, hp, 64, 0, N_NODES);
  k_al1<<<nbN,256,0,stream>>>(hp, fas2, fad2, als4, ald4);
  k_gat_agg1e<<<N_NODES,64,0,stream>>>(rp, col_src, edot1, hp, als4, ald4, fb2, out2);
  k_colstats<64><<<(N_NODES+127)/128,256,0,stream>>>(out2, bn2);
  k_bn_relu<64><<<nb64,256,0,stream>>>(out2, bn2, fg2, fbe2);

  // GCN layer 1
  k_gemm_t<64,true><<<nbT,256,0,stream>>>(out2, 64, fone, fWg1, 64, 0, hp, 64, 0, N_NODES);
  k_gcn_agg<<<N_NODES,64,0,stream>>>(rp, col_src, dinv, hp, fbg1, out3);
  k_colstats<64><<<(N_NODES+127)/128,256,0,stream>>>(out3, bn3);
  k_bn_relu<64><<<nb64,256,0,stream>>>(out3, bn3, fg3, fbe3);

  // GCN layer 2
  k_gemm_t<64,true><<<nbT,256,0,stream>>>(out3, 64, fone, fWg2, 64, 0, hp, 64, 0, N_NODES);
  k_gcn_agg<<<N_NODES,64,0,stream>>>(rp, col_src, dinv, hp, fbg2, out4);
  k_colstats<64><<<(N_NODES+127)/128,256,0,stream>>>(out4, bn4);
  k_bn_relu<64><<<nb64,256,0,stream>>>(out4, bn4, fg4, fbe4);

  // pool + head
  k_pool2<<<nbN,64,0,stream>>>(out4, batch, psum, pcnt);
  k_head<<<N_GRAPHS,128,0,stream>>>(psum, pcnt, f_exf, fWex1, fbex1, fWex2, fbex2,
                                    fWc1, fbc1, fWc2, fbc2, mode, d_out);
}

// Round 6
// 1276.123 us; speedup vs baseline: 1.4772x; 1.0795x over previous
//
#include <hip/hip_runtime.h>
#include <hip/hip_bf16.h>

#define N_NODES 50000
#define N_EDGES 1600000
#define N_GRAPHS 256
#define NEG_SLOPE 0.2f
#define BN_EPS 1e-5f

typedef __hip_bfloat16 bf16;

__device__ __forceinline__ float b2f(bf16 v){ return __bfloat162float(v); }
__device__ __forceinline__ bf16 f2b(float v){ return __float2bfloat16(v); }
__device__ __forceinline__ float us2f(unsigned short u){ return __uint_as_float(((unsigned)u)<<16); }
__device__ __forceinline__ unsigned short f2us(float v){ bf16 b = f2b(v); return *(unsigned short*)&b; }
__device__ __forceinline__ float ldF(const void* p, size_t i, int m){
  return m ? ((const float*)p)[i] : b2f(((const bf16*)p)[i]);
}
__device__ __forceinline__ float sane(float v){
  return (v == v && fabsf(v) < 1e30f) ? v : 0.f;
}
__device__ __forceinline__ float sel4(const float v[4], int h){
  float r = v[0];
  r = (h==1) ? v[1] : r;
  r = (h==2) ? v[2] : r;
  r = (h==3) ? v[3] : r;
  return r;
}

// ---------------- dtype detection ----------------
__global__ void k_detect(const void* x, int* flag){
  if(threadIdx.x == 0 && blockIdx.x == 0){
    const unsigned short* u = (const unsigned short*)x;
    int insane = 0;
    for(int i=0;i<1024;i++){
      float v = fabsf(us2f(u[i]));
      if(!(v > 1e-6f && v < 1e4f)) insane++;
    }
    flag[0] = (insane > 128) ? 1 : 0;  // 1 => data is f32
    flag[1] = 1;
  }
}

// ---------------- weight bank conversion ----------------
#define NSEG 33
struct Bank { const void* p[NSEG]; int n[NSEG]; int off[NSEG]; };

__global__ void k_convert(Bank b, const int* mode, float* out){
  int seg = blockIdx.y;
  int i = blockIdx.x*256 + threadIdx.x;
  int m = *mode;
  if(i < b.n[seg]) out[b.off[seg] + i] = ldF(b.p[seg], i, m);
}

__global__ void k_we(const float* __restrict__ We1, const float* __restrict__ ae1,
                     const float* __restrict__ We2, const float* __restrict__ ae2,
                     float* __restrict__ w_e){
  int t = threadIdx.x;
  if(t < 32){
    int h = t >> 3, k = t & 7;
    float s = 0.f;
    for(int d=0;d<64;d++) s += We1[k*256 + h*64 + d] * ae1[h*64 + d];
    w_e[t] = s;
  } else if(t < 40){
    int k = t - 32;
    float s = 0.f;
    for(int d=0;d<64;d++) s += We2[k*64 + d] * ae2[d];
    w_e[t] = s;
  }
}

// ---------------- CSR build ----------------
__global__ void k_count(const int* __restrict__ dst, int* __restrict__ cnt){
  int e = blockIdx.x*256 + threadIdx.x;
  if(e < N_EDGES){
    int d = dst[e]; if((unsigned)d >= N_NODES) d = 0;
    atomicAdd(&cnt[d], 1);
  }
}

__global__ void k_blocksum(const int* __restrict__ cnt, int* __restrict__ bsum){
  __shared__ int s[256];
  int i = blockIdx.x*256 + threadIdx.x;
  s[threadIdx.x] = (i < N_NODES) ? cnt[i] : 0;
  __syncthreads();
  for(int o=128;o>0;o>>=1){ if(threadIdx.x<o) s[threadIdx.x]+=s[threadIdx.x+o]; __syncthreads(); }
  if(threadIdx.x==0) bsum[blockIdx.x]=s[0];
}

__global__ void k_scan_bsum(const int* __restrict__ bsum, int* __restrict__ bofs, int nb){
  __shared__ int s[256];
  int t = threadIdx.x;
  s[t] = (t<nb) ? bsum[t] : 0;
  __syncthreads();
  for(int o=1;o<256;o<<=1){ int v=(t>=o)?s[t-o]:0; __syncthreads(); s[t]+=v; __syncthreads(); }
  bofs[t] = (t==0) ? 0 : s[t-1];
}

__global__ void k_scan_write(const int* __restrict__ cnt, const int* __restrict__ bofs, int* __restrict__ rp){
  __shared__ int s[256];
  int t = threadIdx.x; int i = blockIdx.x*256 + t;
  int v = (i<N_NODES) ? cnt[i] : 0;
  s[t]=v; __syncthreads();
  for(int o=1;o<256;o<<=1){ int a=(t>=o)?s[t-o]:0; __syncthreads(); s[t]+=a; __syncthreads(); }
  if(i<N_NODES) rp[i+1] = s[t] + bofs[blockIdx.x];
  if(i==0) rp[0]=0;
}

// fill CSR + per-edge attention dot-products (bf16, CSR slot order)
__global__ void k_fill(const int* __restrict__ src, const int* __restrict__ dst,
                       const int* __restrict__ rp, int* __restrict__ fill,
                       const void* __restrict__ ea, const int* __restrict__ mode,
                       const float* __restrict__ w_e,
                       int* __restrict__ col_src,
                       unsigned short* __restrict__ edot4, unsigned short* __restrict__ edot1){
  int e = blockIdx.x*256 + threadIdx.x;
  if(e >= N_EDGES) return;
  int d = dst[e]; if((unsigned)d >= N_NODES) d = 0;
  int p = atomicAdd(&fill[d], 1);
  int slot = rp[d] + p;
  if((unsigned)slot >= N_EDGES) return;
  int sv = src[e]; if((unsigned)sv >= N_NODES) sv = 0;
  col_src[slot] = sv;
  int m = *mode;
  float a[8];
  if(m){
    const float* eaf = (const float*)ea;
    float4 lo = *(const float4*)&eaf[(size_t)e*8];
    float4 hi = *(const float4*)&eaf[(size_t)e*8 + 4];
    a[0]=lo.x; a[1]=lo.y; a[2]=lo.z; a[3]=lo.w;
    a[4]=hi.x; a[5]=hi.y; a[6]=hi.z; a[7]=hi.w;
  } else {
    #pragma unroll
    for(int k=0;k<8;k++) a[k] = b2f(((const bf16*)ea)[(size_t)e*8 + k]);
  }
  unsigned short d4[4];
  #pragma unroll
  for(int h=0;h<4;h++){
    float s = 0.f;
    #pragma unroll
    for(int k=0;k<8;k++) s += a[k]*w_e[h*8+k];
    d4[h] = f2us(s);
  }
  *(ushort4*)&edot4[(size_t)slot*4] = make_ushort4(d4[0],d4[1],d4[2],d4[3]);
  float s1 = 0.f;
  #pragma unroll
  for(int k=0;k<8;k++) s1 += a[k]*w_e[32+k];
  edot1[slot] = f2us(s1);
}

__global__ void k_dinv(const int* __restrict__ rp, float* __restrict__ dinv){
  int n = blockIdx.x*256 + threadIdx.x;
  if(n >= N_NODES) return;
  int s = rp[n], e = rp[n+1];
  int deg = (e >= s) ? (e - s) : 0;
  dinv[n] = rsqrtf((float)deg + 1.f);
}

// ---------------- tiled GEMM ----------------
template<int KIN, bool OUTBF>
__global__ __launch_bounds__(256) void k_gemm_t(
    const void* __restrict__ A, int lda, const int* __restrict__ amode,
    const float* __restrict__ W, int ldw, int woffB,
    void* __restrict__ C, int ldc, int coffB, int M)
{
  __shared__ float As[64][68];
  __shared__ float Ws[64][64];
  const int tid = threadIdx.x;
  const int bm  = blockIdx.x * 64;
  const int woff = woffB + blockIdx.y * 64;
  const int coff = coffB + blockIdx.y * 64;
  const int tx  = tid & 15;
  const int ty  = tid >> 4;
  const int am  = *amode;
  float acc[4][4] = {};

  for(int k0 = 0; k0 < KIN; k0 += 64){
    if(am){
      const float* Af = (const float*)A;
      #pragma unroll
      for(int f = tid; f < 1024; f += 256){
        int r = f >> 4, kq = f & 15;
        int row = bm + r;
        float4 v = make_float4(0.f,0.f,0.f,0.f);
        if(row < M) v = *(const float4*)&Af[(size_t)row*lda + k0 + 4*kq];
        *(float4*)&As[r][4*kq] = v;
      }
    } else {
      const bf16* Ab = (const bf16*)A;
      #pragma unroll
      for(int f = tid; f < 1024; f += 256){
        int r = f >> 4, kq = f & 15;
        int row = bm + r;
        float4 v = make_float4(0.f,0.f,0.f,0.f);
        if(row < M){
          const bf16* p = &Ab[(size_t)row*lda + k0 + 4*kq];
          v = make_float4(b2f(p[0]), b2f(p[1]), b2f(p[2]), b2f(p[3]));
        }
        *(float4*)&As[r][4*kq] = v;
      }
    }
    #pragma unroll
    for(int g = tid; g < 1024; g += 256){
      int kr = g >> 4, jq = g & 15;
      *(float4*)&Ws[kr][4*jq] = *(const float4*)&W[(size_t)(k0+kr)*ldw + woff + 4*jq];
    }
    __syncthreads();
    #pragma unroll
    for(int k = 0; k < 64; k += 4){
      float4 av[4], wv[4];
      #pragma unroll
      for(int r=0;r<4;r++) av[r] = *(const float4*)&As[4*ty + r][k];
      #pragma unroll
      for(int kk=0;kk<4;kk++) wv[kk] = *(const float4*)&Ws[k + kk][4*tx];
      #pragma unroll
      for(int r=0;r<4;r++){
        const float a0=av[r].x, a1=av[r].y, a2=av[r].z, a3=av[r].w;
        acc[r][0] += a0*wv[0].x + a1*wv[1].x + a2*wv[2].x + a3*wv[3].x;
        acc[r][1] += a0*wv[0].y + a1*wv[1].y + a2*wv[2].y + a3*wv[3].y;
        acc[r][2] += a0*wv[0].z + a1*wv[1].z + a2*wv[2].z + a3*wv[3].z;
        acc[r][3] += a0*wv[0].w + a1*wv[1].w + a2*wv[2].w + a3*wv[3].w;
      }
    }
    __syncthreads();
  }
  #pragma unroll
  for(int r=0;r<4;r++){
    int row = bm + 4*ty + r;
    if(row < M){
      if(OUTBF){
        bf16* Cb = (bf16*)C;
        ushort4 u = make_ushort4(f2us(acc[r][0]), f2us(acc[r][1]), f2us(acc[r][2]), f2us(acc[r][3]));
        *(ushort4*)&Cb[(size_t)row*ldc + coff + 4*tx] = u;
      } else {
        float* Cf = (float*)C;
        *(float4*)&Cf[(size_t)row*ldc + coff + 4*tx] =
            make_float4(acc[r][0], acc[r][1], acc[r][2], acc[r][3]);
      }
    }
  }
}

// ---------------- alpha dots ----------------
__global__ void k_al4(const bf16* __restrict__ hp, const float* __restrict__ asrc,
                      const float* __restrict__ adst,
                      float* __restrict__ als4, float* __restrict__ ald4){
  int idx = blockIdx.x*256 + threadIdx.x;
  if(idx >= N_NODES*4) return;
  int n = idx >> 2, h = idx & 3;
  const bf16* row = hp + (size_t)n*256 + h*64;
  float ss=0.f, sd=0.f;
  #pragma unroll 8
  for(int d=0;d<64;d++){ float v=b2f(row[d]); ss += v*asrc[h*64+d]; sd += v*adst[h*64+d]; }
  als4[idx]=ss; ald4[idx]=sd;
}

__global__ void k_al1(const bf16* __restrict__ hp, const float* __restrict__ asrc,
                      const float* __restrict__ adst,
                      float* __restrict__ als, float* __restrict__ ald){
  int n = blockIdx.x*256 + threadIdx.x;
  if(n >= N_NODES) return;
  const bf16* row = hp + (size_t)n*64;
  float ss=0.f, sd=0.f;
  #pragma unroll 8
  for(int d=0;d<64;d++){ float v=b2f(row[d]); ss += v*asrc[d]; sd += v*adst[d]; }
  als[n]=ss; ald[n]=sd;
}

// ---------------- fused 4-head GAT aggregate: ONE WAVE per node ----------------
// lane t owns cols 4t..4t+3 (head = t>>4); per edge one dwordx2 row load.
__global__ __launch_bounds__(64) void k_gat_agg4(
    const int* __restrict__ rp, const int* __restrict__ col_src,
    const unsigned short* __restrict__ edot4,
    const bf16* __restrict__ hp,                 // [N,256]
    const float* __restrict__ als4, const float* __restrict__ ald4,
    const float* __restrict__ bias256, float* __restrict__ out1){
  int n = blockIdx.x; int t = threadIdx.x;
  int head = t >> 4;
  __shared__ int   ssrc[64];
  __shared__ float swt[64][4];
  int s0 = rp[n], e0 = rp[n+1];
  if((unsigned)s0 > N_EDGES){ s0=0; e0=0; }
  if(e0 < s0 || (unsigned)e0 > N_EDGES) e0 = s0;
  float4 aldv = *(const float4*)&ald4[n*4];
  float4 alsvn = *(const float4*)&als4[n*4];
  float wsum[4] = {0.f,0.f,0.f,0.f};
  float dsum[4] = {0.f,0.f,0.f,0.f};
  float acc[4]  = {0.f,0.f,0.f,0.f};
  const unsigned short* hpu = (const unsigned short*)hp;

  for(int base = s0; base < e0; base += 64){
    int m = min(64, e0 - base);
    if(t < m){
      int sn = col_src[base+t]; if((unsigned)sn >= N_NODES) sn = 0;
      ssrc[t] = sn;
      ushort4 ed = *(const ushort4*)&edot4[(size_t)(base+t)*4];
      float4 alss = *(const float4*)&als4[sn*4];
      float edf[4] = {us2f(ed.x), us2f(ed.y), us2f(ed.z), us2f(ed.w)};
      float alssv[4] = {alss.x, alss.y, alss.z, alss.w};
      float aldvv[4] = {aldv.x, aldv.y, aldv.z, aldv.w};
      float w4[4];
      #pragma unroll
      for(int h=0;h<4;h++){
        float sc = alssv[h] + aldvv[h] + edf[h];
        sc = sc > 0.f ? sc : NEG_SLOPE*sc;
        sc = fminf(sc, 30.f);
        float w = expf(sc);
        w4[h] = w;
        wsum[h] += w; dsum[h] += edf[h];
      }
      *(float4*)&swt[t][0] = make_float4(w4[0], w4[1], w4[2], w4[3]);
    }
    __syncthreads();
    #pragma unroll 4
    for(int i=0;i<m;i++){
      int row = ssrc[i];
      float w = swt[i][head];
      ushort4 u = *(const ushort4*)&hpu[(size_t)row*256 + 4*t];
      acc[0] += w*us2f(u.x); acc[1] += w*us2f(u.y);
      acc[2] += w*us2f(u.z); acc[3] += w*us2f(u.w);
    }
    __syncthreads();
  }
  // butterfly across 64 lanes for wsum/dsum
  #pragma unroll
  for(int o=1;o<64;o<<=1){
    #pragma unroll
    for(int h=0;h<4;h++){
      wsum[h] += __shfl_xor(wsum[h], o);
      dsum[h] += __shfl_xor(dsum[h], o);
    }
  }
  float alsnv[4] = {alsvn.x, alsvn.y, alsvn.z, alsvn.w};
  float aldnv[4] = {aldv.x, aldv.y, aldv.z, aldv.w};
  float sEh = sel4(wsum, head), sDh = sel4(dsum, head);
  float deg = (float)(e0 - s0);
  float sdot = deg > 0.f ? sDh/deg : 0.f;
  float sc = sel4(alsnv, head) + sel4(aldnv, head) + sdot;
  sc = sc > 0.f ? sc : NEG_SLOPE*sc;
  sc = fminf(sc, 30.f);
  float wself = expf(sc);
  ushort4 su = *(const ushort4*)&hpu[(size_t)n*256 + 4*t];
  float4 bi = *(const float4*)&bias256[4*t];
  float inv = 1.f/(sEh + wself);
  float4 o4;
  o4.x = (acc[0] + wself*us2f(su.x))*inv + bi.x;
  o4.y = (acc[1] + wself*us2f(su.y))*inv + bi.y;
  o4.z = (acc[2] + wself*us2f(su.z))*inv + bi.z;
  o4.w = (acc[3] + wself*us2f(su.w))*inv + bi.w;
  *(float4*)&out1[(size_t)n*256 + 4*t] = o4;
}

// ---------------- single-head GAT aggregate: ONE WAVE per node, 4 edges/iter ----------------
__global__ __launch_bounds__(64) void k_gat_agg1e(
    const int* __restrict__ rp, const int* __restrict__ col_src,
    const unsigned short* __restrict__ edot1,
    const bf16* __restrict__ hp,                 // [N,64]
    const float* __restrict__ als, const float* __restrict__ ald,
    const float* __restrict__ bias64, float* __restrict__ out){
  int n = blockIdx.x; int t = threadIdx.x;
  int eg = t >> 4, cq = t & 15;
  __shared__ float sw[64];
  __shared__ int   ssrc[64];
  int s0 = rp[n], e0 = rp[n+1];
  if((unsigned)s0 > N_EDGES){ s0=0; e0=0; }
  if(e0 < s0 || (unsigned)e0 > N_EDGES) e0 = s0;
  float aldn = ald[n];
  float wsum_l = 0.f, dsum_l = 0.f;
  float acc[4] = {0.f,0.f,0.f,0.f};
  const unsigned short* hpu = (const unsigned short*)hp;
  for(int base = s0; base < e0; base += 64){
    int m = min(64, e0 - base);
    if(t < m){
      int sn = col_src[base+t]; if((unsigned)sn >= N_NODES) sn = 0;
      ssrc[t] = sn;
      float ed = us2f(edot1[base+t]);
      float sc = als[sn] + aldn + ed;
      sc = sc > 0.f ? sc : NEG_SLOPE*sc;
      sc = fminf(sc, 30.f);
      float w = expf(sc);
      sw[t] = w;
      wsum_l += w; dsum_l += ed;
    }
    __syncthreads();
    #pragma unroll 2
    for(int i=0;i<m;i+=4){
      int j = i + eg;
      if(j < m){
        int row = ssrc[j];
        float w = sw[j];
        ushort4 u = *(const ushort4*)&hpu[(size_t)row*64 + 4*cq];
        acc[0] += w*us2f(u.x); acc[1] += w*us2f(u.y);
        acc[2] += w*us2f(u.z); acc[3] += w*us2f(u.w);
      }
    }
    __syncthreads();
  }
  #pragma unroll
  for(int o=1;o<64;o<<=1){ wsum_l += __shfl_xor(wsum_l, o); dsum_l += __shfl_xor(dsum_l, o); }
  #pragma unroll
  for(int q=0;q<4;q++){ acc[q] += __shfl_xor(acc[q], 16); acc[q] += __shfl_xor(acc[q], 32); }
  if(t < 16){
    float deg = (float)(e0 - s0);
    float sdot = deg > 0.f ? dsum_l/deg : 0.f;
    float sc = als[n] + aldn + sdot;
    sc = sc > 0.f ? sc : NEG_SLOPE*sc;
    sc = fminf(sc, 30.f);
    float wself = expf(sc);
    ushort4 su = *(const ushort4*)&hpu[(size_t)n*64 + 4*cq];
    float4 bi = *(const float4*)&bias64[4*cq];
    float inv = 1.f/(wsum_l + wself);
    float4 o4;
    o4.x = (acc[0] + wself*us2f(su.x))*inv + bi.x;
    o4.y = (acc[1] + wself*us2f(su.y))*inv + bi.y;
    o4.z = (acc[2] + wself*us2f(su.z))*inv + bi.z;
    o4.w = (acc[3] + wself*us2f(su.w))*inv + bi.w;
    *(float4*)&out[(size_t)n*64 + 4*cq] = o4;
  }
}

// ---------------- GCN aggregate: ONE WAVE per node, 4 edges/iter ----------------
__global__ __launch_bounds__(64) void k_gcn_agg(
    const int* __restrict__ rp, const int* __restrict__ col_src,
    const float* __restrict__ dinv, const bf16* __restrict__ gp,
    const float* __restrict__ bias, float* __restrict__ out){
  int n = blockIdx.x; int t = threadIdx.x;
  int eg = t >> 4, cq = t & 15;
  __shared__ float sw[64];
  __shared__ int   ssrc[64];
  int s0 = rp[n], e0 = rp[n+1];
  if((unsigned)s0 > N_EDGES){ s0=0; e0=0; }
  if(e0 < s0 || (unsigned)e0 > N_EDGES) e0 = s0;
  float dn = dinv[n];
  float acc[4] = {0.f,0.f,0.f,0.f};
  const unsigned short* gpu = (const unsigned short*)gp;
  for(int base = s0; base < e0; base += 64){
    int m = min(64, e0 - base);
    if(t < m){
      int sn = col_src[base+t]; if((unsigned)sn >= N_NODES) sn = 0;
      ssrc[t]=sn; sw[t]=dinv[sn];
    }
    __syncthreads();
    #pragma unroll 2
    for(int i=0;i<m;i+=4){
      int j = i + eg;
      if(j < m){
        int row = ssrc[j];
        float w = sw[j];
        ushort4 u = *(const ushort4*)&gpu[(size_t)row*64 + 4*cq];
        acc[0] += w*us2f(u.x); acc[1] += w*us2f(u.y);
        acc[2] += w*us2f(u.z); acc[3] += w*us2f(u.w);
      }
    }
    __syncthreads();
  }
  #pragma unroll
  for(int q=0;q<4;q++){ acc[q] += __shfl_xor(acc[q], 16); acc[q] += __shfl_xor(acc[q], 32); }
  if(t < 16){
    ushort4 su = *(const ushort4*)&gpu[(size_t)n*64 + 4*cq];
    float4 bi = *(const float4*)&bias[4*cq];
    float4 o4;
    o4.x = dn*(acc[0] + dn*us2f(su.x)) + bi.x;
    o4.y = dn*(acc[1] + dn*us2f(su.y)) + bi.y;
    o4.z = dn*(acc[2] + dn*us2f(su.z)) + bi.z;
    o4.w = dn*(acc[3] + dn*us2f(su.w)) + bi.w;
    *(float4*)&out[(size_t)n*64 + 4*cq] = o4;
  }
}

// ---------------- BN stats + apply ----------------
template<int C>
__global__ void k_colstats(const float* __restrict__ X, float* __restrict__ sums){
  constexpr int RPB = 128;
  constexpr int RSTEP = 256 / C;
  int c = threadIdx.x % C;
  int r0 = threadIdx.x / C;
  int rbeg = blockIdx.x * RPB;
  int rend = min(N_NODES, rbeg + RPB);
  float s = 0.f, q = 0.f;
  for(int r = rbeg + r0; r < rend; r += RSTEP){
    float v = sane(X[(size_t)r*C + c]);
    s += v; q += v*v;
  }
  atomicAdd(&sums[c], s);
  atomicAdd(&sums[C + c], q);
}

template<int C>
__global__ void k_bn_relu(float* __restrict__ X, const float* __restrict__ sums,
                          const float* __restrict__ g, const float* __restrict__ b){
  int idx = blockIdx.x*256 + threadIdx.x;
  if(idx >= N_NODES*C) return;
  int c = idx % C;
  const float invN = 1.0f / (float)N_NODES;
  float mean = sums[c]*invN;
  float var = fmaxf(sums[C+c]*invN - mean*mean, 0.f);
  float y = (sane(X[idx])-mean)*rsqrtf(var + BN_EPS)*g[c] + b[c];
  X[idx] = fmaxf(y, 0.f);
}

// ---------------- mean pool (sorted batch, segmented) ----------------
__global__ __launch_bounds__(64) void k_pool2(
    const float* __restrict__ h, const int* __restrict__ batch,
    float* __restrict__ psum, float* __restrict__ pcnt){
  int t = threadIdx.x;
  int n0 = blockIdx.x * 256;
  int n1 = min(N_NODES, n0 + 256);
  if(n0 >= n1) return;
  int cur = batch[n0]; if((unsigned)cur >= N_GRAPHS) cur = 0;
  float acc = 0.f; int cl = 0;
  for(int n = n0; n < n1; n++){
    int g = batch[n]; if((unsigned)g >= N_GRAPHS) g = 0;
    if(g != cur){
      atomicAdd(&psum[cur*64 + t], acc);
      if(t == 0) atomicAdd(&pcnt[cur], (float)cl);
      acc = 0.f; cl = 0; cur = g;
    }
    acc += h[(size_t)n*64 + t];
    cl++;
  }
  atomicAdd(&psum[cur*64 + t], acc);
  if(t == 0) atomicAdd(&pcnt[cur], (float)cl);
}

// ---------------- head MLPs + output ----------------
__device__ __forceinline__ void stO(void* o, size_t i, float v, int m){
  if(m) ((float*)o)[i] = v; else ((bf16*)o)[i] = f2b(v);
}

__global__ __launch_bounds__(128) void k_head(
    const float* __restrict__ psum, const float* __restrict__ pcnt,
    const float* __restrict__ exf,
    const float* __restrict__ Wex1, const float* __restrict__ bex1,
    const float* __restrict__ Wex2, const float* __restrict__ bex2,
    const float* __restrict__ Wc1, const float* __restrict__ bc1,
    const float* __restrict__ Wc2, const float* __restrict__ bc2,
    const int* __restrict__ mode, void* __restrict__ dout){
  int g = blockIdx.x; int t = threadIdx.x;
  int m0 = *mode;
  __shared__ float ci[128];
  __shared__ float e1[64];
  __shared__ float comb[128];
  __shared__ float red[128];
  if(t < 64){
    float c = fmaxf(pcnt[g], 1.f);
    float xp = sane(psum[g*64 + t]) / c;
    ci[t] = xp;
    stO(dout, 256 + (size_t)g*64 + t, xp, m0);
  } else {
    int j = t - 64;
    float s = bex1[j];
    for(int k=0;k<32;k++) s += exf[g*32 + k] * Wex1[k*64 + j];
    e1[j] = fmaxf(s, 0.f);
  }
  __syncthreads();
  if(t >= 64){
    int j = t - 64;
    float s = bex2[j];
    for(int k=0;k<64;k++) s += e1[k] * Wex2[k*64 + j];
    ci[64 + j] = fmaxf(s, 0.f);
  }
  __syncthreads();
  {
    float s = bc1[t];
    for(int k=0;k<128;k++) s += ci[k] * Wc1[k*128 + t];
    s = fmaxf(s, 0.f);
    comb[t] = s;
    stO(dout, 256 + 16384 + (size_t)g*128 + t, s, m0);
  }
  __syncthreads();
  red[t] = comb[t] * Wc2[t];
  __syncthreads();
  for(int o=64;o>0;o>>=1){ if(t<o) red[t]+=red[t+o]; __syncthreads(); }
  if(t==0) stO(dout, g, red[0] + bc2[0], m0);
}

// ---------------- launch ----------------
extern "C" void kernel_launch(void* const* d_in, const int* in_sizes, int n_in,
                              void* d_out, int out_size, void* d_ws, size_t ws_size,
                              hipStream_t stream){
  const void* x    = d_in[0];
  const void* ea   = d_in[1];
  const int* ei    = (const int*)d_in[3];
  const int* batch = (const int*)d_in[4];
  const int* src = ei;
  const int* dst = ei + N_EDGES;

  char* base = (char*)d_ws;
  size_t off = 0;
  auto alloc = [&](size_t bytes) -> void* {
    void* r = base + off;
    off += (bytes + 255) & ~(size_t)255;
    return r;
  };
  int*   cnt    = (int*)  alloc((size_t)N_NODES*4);
  int*   fill   = (int*)  alloc((size_t)N_NODES*4);
  float* bnstat = (float*)alloc(4096);
  float* pool   = (float*)alloc((size_t)(N_GRAPHS*64 + N_GRAPHS)*4);
  size_t zbytes = off;
  int*   rp      = (int*)  alloc((size_t)(N_NODES+1)*4);
  int*   bsum    = (int*)  alloc(256*4);
  int*   bofs    = (int*)  alloc(256*4);
  int*   col_src = (int*)  alloc((size_t)N_EDGES*4);
  unsigned short* edot4 = (unsigned short*)alloc((size_t)N_EDGES*4*2);
  unsigned short* edot1 = (unsigned short*)alloc((size_t)N_EDGES*2);
  float* dinv    = (float*)alloc((size_t)N_NODES*4);
  float* w_e     = (float*)alloc(64*4);
  float* als4    = (float*)alloc((size_t)N_NODES*4*4);
  float* ald4    = (float*)alloc((size_t)N_NODES*4*4);
  int*   mode    = (int*)  alloc(8);
  float* wbank   = (float*)alloc(80000*4);
  bf16*  hp      = (bf16*) alloc((size_t)N_NODES*256*2);
  float* out1    = (float*)alloc((size_t)N_NODES*256*4);

  float* out2 = out1;
  float* out3 = out1 + (size_t)N_NODES*64;
  float* out4 = out1 + (size_t)N_NODES*128;
  float* bn1 = bnstat;
  float* bn2 = bnstat + 512;
  float* bn3 = bnstat + 640;
  float* bn4 = bnstat + 768;
  float* psum = pool;
  float* pcnt = pool + N_GRAPHS*64;
  int* fone = mode + 1;

  const int segidx[NSEG] = {2, 5,6,7,8,9,10,11,12, 13,14,15,16,17,18,19,20,
                            21,22,23,24, 25,26,27,28, 29,30,31,32, 33,34,35,36};
  const int segn[NSEG] = {8192, 16384,256,256,2048,256,256,256,256,
                          16384,64,64,512,64,64,64,64,
                          4096,64,64,64, 4096,64,64,64,
                          2048,64,4096,64, 16384,128,128,1};
  Bank bk;
  int offs[NSEG]; int acc0 = 0;
  for(int i=0;i<NSEG;i++){ bk.p[i]=d_in[segidx[i]]; bk.n[i]=segn[i]; bk.off[i]=acc0; offs[i]=acc0; acc0+=segn[i]; }
  const float* f_exf = wbank + offs[0];
  const float* fW1 = wbank+offs[1]; const float* fas1 = wbank+offs[2]; const float* fad1 = wbank+offs[3];
  const float* fWe1= wbank+offs[4]; const float* fae1 = wbank+offs[5]; const float* fb1  = wbank+offs[6];
  const float* fg1 = wbank+offs[7]; const float* fbe1 = wbank+offs[8];
  const float* fW2 = wbank+offs[9]; const float* fas2 = wbank+offs[10]; const float* fad2 = wbank+offs[11];
  const float* fWe2= wbank+offs[12]; const float* fae2 = wbank+offs[13]; const float* fb2 = wbank+offs[14];
  const float* fg2 = wbank+offs[15]; const float* fbe2 = wbank+offs[16];
  const float* fWg1= wbank+offs[17]; const float* fbg1 = wbank+offs[18]; const float* fg3 = wbank+offs[19];
  const float* fbe3= wbank+offs[20];
  const float* fWg2= wbank+offs[21]; const float* fbg2 = wbank+offs[22]; const float* fg4 = wbank+offs[23];
  const float* fbe4= wbank+offs[24];
  const float* fWex1=wbank+offs[25]; const float* fbex1= wbank+offs[26];
  const float* fWex2=wbank+offs[27]; const float* fbex2= wbank+offs[28];
  const float* fWc1= wbank+offs[29]; const float* fbc1 = wbank+offs[30];
  const float* fWc2= wbank+offs[31]; const float* fbc2 = wbank+offs[32];

  const int nbN  = (N_NODES + 255)/256;
  const int nbE  = (N_EDGES + 255)/256;
  const int nb64 = (N_NODES*64 + 255)/256;
  const int nbT  = (N_NODES + 63)/64;

  hipMemsetAsync(d_ws, 0, zbytes, stream);
  k_detect<<<1,64,0,stream>>>(x, mode);
  {
    dim3 g((16384+255)/256, NSEG);
    k_convert<<<g,256,0,stream>>>(bk, mode, wbank);
  }
  k_we<<<1,64,0,stream>>>(fWe1, fae1, fWe2, fae2, w_e);
  k_count<<<nbE,256,0,stream>>>(dst, cnt);
  k_blocksum<<<nbN,256,0,stream>>>(cnt, bsum);
  k_scan_bsum<<<1,256,0,stream>>>(bsum, bofs, nbN);
  k_scan_write<<<nbN,256,0,stream>>>(cnt, bofs, rp);
  k_fill<<<nbE,256,0,stream>>>(src, dst, rp, fill, ea, mode, w_e, col_src, edot4, edot1);
  k_dinv<<<nbN,256,0,stream>>>(rp, dinv);

  // GAT layer 1 (4 heads fused)
  {
    dim3 g(nbT, 4);
    k_gemm_t<64,true><<<g,256,0,stream>>>(x, 64, mode, fW1, 256, 0, hp, 256, 0, N_NODES);
  }
  k_al4<<<(N_NODES*4+255)/256,256,0,stream>>>(hp, fas1, fad1, als4, ald4);
  k_gat_agg4<<<N_NODES,64,0,stream>>>(rp, col_src, edot4, hp, als4, ald4, fb1, out1);
  k_colstats<256><<<(N_NODES+127)/128,256,0,stream>>>(out1, bn1);
  k_bn_relu<256><<<(N_NODES*256+255)/256,256,0,stream>>>(out1, bn1, fg1, fbe1);

  // GAT layer 2 (1 head)
  k_gemm_t<256,true><<<nbT,256,0,stream>>>(out1, 256, fone, fW2, 64, 0, hp, 64, 0, N_NODES);
  k_al1<<<nbN,256,0,stream>>>(hp, fas2, fad2, als4, ald4);
  k_gat_agg1e<<<N_NODES,64,0,stream>>>(rp, col_src, edot1, hp, als4, ald4, fb2, out2);
  k_colstats<64><<<(N_NODES+127)/128,256,0,stream>>>(out2, bn2);
  k_bn_relu<64><<<nb64,256,0,stream>>>(out2, bn2, fg2, fbe2);

  // GCN layer 1
  k_gemm_t<64,true><<<nbT,256,0,stream>>>(out2, 64, fone, fWg1, 64, 0, hp, 64, 0, N_NODES);
  k_gcn_agg<<<N_NODES,64,0,stream>>>(rp, col_src, dinv, hp, fbg1, out3);
  k_colstats<64><<<(N_NODES+127)/128,256,0,stream>>>(out3, bn3);
  k_bn_relu<64><<<nb64,256,0,stream>>>(out3, bn3, fg3, fbe3);

  // GCN layer 2
  k_gemm_t<64,true><<<nbT,256,0,stream>>>(out3, 64, fone, fWg2, 64, 0, hp, 64, 0, N_NODES);
  k_gcn_agg<<<N_NODES,64,0,stream>>>(rp, col_src, dinv, hp, fbg2, out4);
  k_colstats<64><<<(N_NODES+127)/128,256,0,stream>>>(out4, bn4);
  k_bn_relu<64><<<nb64,256,0,stream>>>(out4, bn4, fg4, fbe4);

  // pool + head
  k_pool2<<<nbN,64,0,stream>>>(out4, batch, psum, pcnt);
  k_head<<<N_GRAPHS,128,0,stream>>>(psum, pcnt, f_exf, fWex1, fbex1, fWex2, fbex2,
                                    fWc1, fbc1, fWc2, fbc2, mode, d_out);
}

// Round 7
// 1161.782 us; speedup vs baseline: 1.6226x; 1.0984x over previous
//
#include <hip/hip_runtime.h>
#include <hip/hip_bf16.h>

#define N_NODES 50000
#define N_EDGES 1600000
#define N_GRAPHS 256
#define NEG_SLOPE 0.2f
#define BN_EPS 1e-5f

typedef __hip_bfloat16 bf16;

__device__ __forceinline__ float b2f(bf16 v){ return __bfloat162float(v); }
__device__ __forceinline__ bf16 f2b(float v){ return __float2bfloat16(v); }
__device__ __forceinline__ float us2f(unsigned short u){ return __uint_as_float(((unsigned)u)<<16); }
__device__ __forceinline__ unsigned short f2us(float v){ bf16 b = f2b(v); return *(unsigned short*)&b; }
__device__ __forceinline__ float ldF(const void* p, size_t i, int m){
  return m ? ((const float*)p)[i] : b2f(((const bf16*)p)[i]);
}
__device__ __forceinline__ float sane(float v){
  return (v == v && fabsf(v) < 1e30f) ? v : 0.f;
}
__device__ __forceinline__ float sel4(const float v[4], int h){
  float r = v[0];
  r = (h==1) ? v[1] : r;
  r = (h==2) ? v[2] : r;
  r = (h==3) ? v[3] : r;
  return r;
}

// ---------------- dtype detection (one wave) ----------------
__global__ void k_detect(const void* x, int* flag){
  int t = threadIdx.x;
  const unsigned short* u = (const unsigned short*)x;
  int insane = 0;
  for(int i=t;i<1024;i+=64){
    float v = fabsf(us2f(u[i]));
    if(!(v > 1e-6f && v < 1e4f)) insane++;
  }
  #pragma unroll
  for(int o=1;o<64;o<<=1) insane += __shfl_xor(insane, o);
  if(t == 0){
    flag[0] = (insane > 128) ? 1 : 0;  // 1 => data is f32
    flag[1] = 1;
  }
}

// ---------------- weight bank conversion ----------------
#define NSEG 33
struct Bank { const void* p[NSEG]; int n[NSEG]; int off[NSEG]; };

__global__ void k_convert(Bank b, const int* mode, float* out){
  int seg = blockIdx.y;
  int i = blockIdx.x*256 + threadIdx.x;
  int m = *mode;
  if(i < b.n[seg]) out[b.off[seg] + i] = ldF(b.p[seg], i, m);
}

__global__ void k_we(const float* __restrict__ We1, const float* __restrict__ ae1,
                     const float* __restrict__ We2, const float* __restrict__ ae2,
                     float* __restrict__ w_e){
  int t = threadIdx.x;
  if(t < 32){
    int h = t >> 3, k = t & 7;
    float s = 0.f;
    for(int d=0;d<64;d++) s += We1[k*256 + h*64 + d] * ae1[h*64 + d];
    w_e[t] = s;
  } else if(t < 40){
    int k = t - 32;
    float s = 0.f;
    for(int d=0;d<64;d++) s += We2[k*64 + d] * ae2[d];
    w_e[t] = s;
  }
}

// ---------------- CSR build ----------------
__global__ void k_count(const int* __restrict__ dst, int* __restrict__ cnt){
  int e = blockIdx.x*256 + threadIdx.x;
  if(e < N_EDGES){
    int d = dst[e]; if((unsigned)d >= N_NODES) d = 0;
    atomicAdd(&cnt[d], 1);
  }
}

__global__ void k_blocksum(const int* __restrict__ cnt, int* __restrict__ bsum){
  __shared__ int s[256];
  int i = blockIdx.x*256 + threadIdx.x;
  s[threadIdx.x] = (i < N_NODES) ? cnt[i] : 0;
  __syncthreads();
  for(int o=128;o>0;o>>=1){ if(threadIdx.x<o) s[threadIdx.x]+=s[threadIdx.x+o]; __syncthreads(); }
  if(threadIdx.x==0) bsum[blockIdx.x]=s[0];
}

__global__ void k_scan_bsum(const int* __restrict__ bsum, int* __restrict__ bofs, int nb){
  __shared__ int s[256];
  int t = threadIdx.x;
  s[t] = (t<nb) ? bsum[t] : 0;
  __syncthreads();
  for(int o=1;o<256;o<<=1){ int v=(t>=o)?s[t-o]:0; __syncthreads(); s[t]+=v; __syncthreads(); }
  bofs[t] = (t==0) ? 0 : s[t-1];
}

__global__ void k_scan_write(const int* __restrict__ cnt, const int* __restrict__ bofs, int* __restrict__ rp){
  __shared__ int s[256];
  int t = threadIdx.x; int i = blockIdx.x*256 + t;
  int v = (i<N_NODES) ? cnt[i] : 0;
  s[t]=v; __syncthreads();
  for(int o=1;o<256;o<<=1){ int a=(t>=o)?s[t-o]:0; __syncthreads(); s[t]+=a; __syncthreads(); }
  if(i<N_NODES) rp[i+1] = s[t] + bofs[blockIdx.x];
  if(i==0) rp[0]=0;
}

// fill CSR: one packed 16B record per slot = {src, edot4[4] bf16, edot1 bf16}
__global__ void k_fill(const int* __restrict__ src, const int* __restrict__ dst,
                       const int* __restrict__ rp, int* __restrict__ fill,
                       const void* __restrict__ ea, const int* __restrict__ mode,
                       const float* __restrict__ w_e,
                       int4* __restrict__ epk){
  int e = blockIdx.x*256 + threadIdx.x;
  if(e >= N_EDGES) return;
  int d = dst[e]; if((unsigned)d >= N_NODES) d = 0;
  int p = atomicAdd(&fill[d], 1);
  int slot = rp[d] + p;
  if((unsigned)slot >= N_EDGES) return;
  int sv = src[e]; if((unsigned)sv >= N_NODES) sv = 0;
  int m = *mode;
  float a[8];
  if(m){
    const float* eaf = (const float*)ea;
    float4 lo = *(const float4*)&eaf[(size_t)e*8];
    float4 hi = *(const float4*)&eaf[(size_t)e*8 + 4];
    a[0]=lo.x; a[1]=lo.y; a[2]=lo.z; a[3]=lo.w;
    a[4]=hi.x; a[5]=hi.y; a[6]=hi.z; a[7]=hi.w;
  } else {
    #pragma unroll
    for(int k=0;k<8;k++) a[k] = b2f(((const bf16*)ea)[(size_t)e*8 + k]);
  }
  unsigned d4[4];
  #pragma unroll
  for(int h=0;h<4;h++){
    float s = 0.f;
    #pragma unroll
    for(int k=0;k<8;k++) s += a[k]*w_e[h*8+k];
    d4[h] = f2us(s);
  }
  float s1 = 0.f;
  #pragma unroll
  for(int k=0;k<8;k++) s1 += a[k]*w_e[32+k];
  int4 pk;
  pk.x = sv;
  pk.y = (int)(d4[0] | (d4[1] << 16));
  pk.z = (int)(d4[2] | (d4[3] << 16));
  pk.w = (int)(unsigned)f2us(s1);
  epk[slot] = pk;
}

__global__ void k_dinv(const int* __restrict__ rp, float* __restrict__ dinv){
  int n = blockIdx.x*256 + threadIdx.x;
  if(n >= N_NODES) return;
  int s = rp[n], e = rp[n+1];
  int deg = (e >= s) ? (e - s) : 0;
  dinv[n] = rsqrtf((float)deg + 1.f);
}

// ---------------- tiled GEMM (optional fused BN+ReLU on f32 A-load) ----------------
template<int KIN, bool OUTBF, bool BNF>
__global__ __launch_bounds__(256) void k_gemm_t(
    const void* __restrict__ A, int lda, const int* __restrict__ amode,
    const float* __restrict__ W, int ldw, int woffB,
    void* __restrict__ C, int ldc, int coffB, int M,
    const float* __restrict__ bnsums, const float* __restrict__ bng, const float* __restrict__ bnb)
{
  __shared__ float As[64][68];
  __shared__ float Ws[64][64];
  const int tid = threadIdx.x;
  const int bm  = blockIdx.x * 64;
  const int woff = woffB + blockIdx.y * 64;
  const int coff = coffB + blockIdx.y * 64;
  const int tx  = tid & 15;
  const int ty  = tid >> 4;
  const int am  = *amode;
  const float invN = 1.0f / (float)N_NODES;
  float acc[4][4] = {};

  for(int k0 = 0; k0 < KIN; k0 += 64){
    if(am){
      const float* Af = (const float*)A;
      #pragma unroll
      for(int f = tid; f < 1024; f += 256){
        int r = f >> 4, kq = f & 15;
        int row = bm + r;
        float4 v = make_float4(0.f,0.f,0.f,0.f);
        if(row < M) v = *(const float4*)&Af[(size_t)row*lda + k0 + 4*kq];
        if(BNF){
          int c = k0 + 4*kq;
          float vv[4] = {v.x, v.y, v.z, v.w};
          #pragma unroll
          for(int j=0;j<4;j++){
            int cc = c + j;
            float mean = bnsums[cc]*invN;
            float var = fmaxf(bnsums[KIN+cc]*invN - mean*mean, 0.f);
            float y = (sane(vv[j])-mean)*rsqrtf(var + BN_EPS)*bng[cc] + bnb[cc];
            vv[j] = fmaxf(y, 0.f);
          }
          v = make_float4(vv[0], vv[1], vv[2], vv[3]);
        }
        *(float4*)&As[r][4*kq] = v;
      }
    } else {
      const bf16* Ab = (const bf16*)A;
      #pragma unroll
      for(int f = tid; f < 1024; f += 256){
        int r = f >> 4, kq = f & 15;
        int row = bm + r;
        float4 v = make_float4(0.f,0.f,0.f,0.f);
        if(row < M){
          const bf16* p = &Ab[(size_t)row*lda + k0 + 4*kq];
          v = make_float4(b2f(p[0]), b2f(p[1]), b2f(p[2]), b2f(p[3]));
        }
        *(float4*)&As[r][4*kq] = v;
      }
    }
    #pragma unroll
    for(int g = tid; g < 1024; g += 256){
      int kr = g >> 4, jq = g & 15;
      *(float4*)&Ws[kr][4*jq] = *(const float4*)&W[(size_t)(k0+kr)*ldw + woff + 4*jq];
    }
    __syncthreads();
    #pragma unroll
    for(int k = 0; k < 64; k += 4){
      float4 av[4], wv[4];
      #pragma unroll
      for(int r=0;r<4;r++) av[r] = *(const float4*)&As[4*ty + r][k];
      #pragma unroll
      for(int kk=0;kk<4;kk++) wv[kk] = *(const float4*)&Ws[k + kk][4*tx];
      #pragma unroll
      for(int r=0;r<4;r++){
        const float a0=av[r].x, a1=av[r].y, a2=av[r].z, a3=av[r].w;
        acc[r][0] += a0*wv[0].x + a1*wv[1].x + a2*wv[2].x + a3*wv[3].x;
        acc[r][1] += a0*wv[0].y + a1*wv[1].y + a2*wv[2].y + a3*wv[3].y;
        acc[r][2] += a0*wv[0].z + a1*wv[1].z + a2*wv[2].z + a3*wv[3].z;
        acc[r][3] += a0*wv[0].w + a1*wv[1].w + a2*wv[2].w + a3*wv[3].w;
      }
    }
    __syncthreads();
  }
  #pragma unroll
  for(int r=0;r<4;r++){
    int row = bm + 4*ty + r;
    if(row < M){
      if(OUTBF){
        bf16* Cb = (bf16*)C;
        ushort4 u = make_ushort4(f2us(acc[r][0]), f2us(acc[r][1]), f2us(acc[r][2]), f2us(acc[r][3]));
        *(ushort4*)&Cb[(size_t)row*ldc + coff + 4*tx] = u;
      } else {
        float* Cf = (float*)C;
        *(float4*)&Cf[(size_t)row*ldc + coff + 4*tx] =
            make_float4(acc[r][0], acc[r][1], acc[r][2], acc[r][3]);
      }
    }
  }
}

// ---------------- alpha dots ----------------
__global__ void k_al4(const bf16* __restrict__ hp, const float* __restrict__ asrc,
                      const float* __restrict__ adst,
                      float* __restrict__ als4, float* __restrict__ ald4){
  int idx = blockIdx.x*256 + threadIdx.x;
  if(idx >= N_NODES*4) return;
  int n = idx >> 2, h = idx & 3;
  const bf16* row = hp + (size_t)n*256 + h*64;
  float ss=0.f, sd=0.f;
  #pragma unroll 8
  for(int d=0;d<64;d++){ float v=b2f(row[d]); ss += v*asrc[h*64+d]; sd += v*adst[h*64+d]; }
  als4[idx]=ss; ald4[idx]=sd;
}

__global__ void k_al1(const bf16* __restrict__ hp, const float* __restrict__ asrc,
                      const float* __restrict__ adst,
                      float* __restrict__ als, float* __restrict__ ald){
  int n = blockIdx.x*256 + threadIdx.x;
  if(n >= N_NODES) return;
  const bf16* row = hp + (size_t)n*64;
  float ss=0.f, sd=0.f;
  #pragma unroll 8
  for(int d=0;d<64;d++){ float v=b2f(row[d]); ss += v*asrc[d]; sd += v*adst[d]; }
  als[n]=ss; ald[n]=sd;
}

// ---------------- fused 4-head GAT aggregate: ONE WAVE per node ----------------
__global__ __launch_bounds__(64) void k_gat_agg4(
    const int* __restrict__ rp, const int4* __restrict__ epk,
    const bf16* __restrict__ hp,                 // [N,256]
    const float* __restrict__ als4, const float* __restrict__ ald4,
    const float* __restrict__ bias256, float* __restrict__ out1){
  int n = blockIdx.x; int t = threadIdx.x;
  int head = t >> 4;
  __shared__ int   ssrc[64];
  __shared__ float swt[64][4];
  int s0 = rp[n], e0 = rp[n+1];
  if((unsigned)s0 > N_EDGES){ s0=0; e0=0; }
  if(e0 < s0 || (unsigned)e0 > N_EDGES) e0 = s0;
  float4 aldv = *(const float4*)&ald4[n*4];
  float4 alsvn = *(const float4*)&als4[n*4];
  float wsum[4] = {0.f,0.f,0.f,0.f};
  float dsum[4] = {0.f,0.f,0.f,0.f};
  float acc[4]  = {0.f,0.f,0.f,0.f};
  const unsigned short* hpu = (const unsigned short*)hp;

  for(int base = s0; base < e0; base += 64){
    int m = min(64, e0 - base);
    if(t < m){
      int4 pk = epk[base+t];
      int sn = pk.x; if((unsigned)sn >= N_NODES) sn = 0;
      ssrc[t] = sn;
      float edf[4] = {us2f((unsigned short)(pk.y & 0xffff)), us2f((unsigned short)((unsigned)pk.y >> 16)),
                      us2f((unsigned short)(pk.z & 0xffff)), us2f((unsigned short)((unsigned)pk.z >> 16))};
      float4 alss = *(const float4*)&als4[sn*4];
      float alssv[4] = {alss.x, alss.y, alss.z, alss.w};
      float aldvv[4] = {aldv.x, aldv.y, aldv.z, aldv.w};
      float w4[4];
      #pragma unroll
      for(int h=0;h<4;h++){
        float sc = alssv[h] + aldvv[h] + edf[h];
        sc = sc > 0.f ? sc : NEG_SLOPE*sc;
        sc = fminf(sc, 30.f);
        float w = expf(sc);
        w4[h] = w;
        wsum[h] += w; dsum[h] += edf[h];
      }
      *(float4*)&swt[t][0] = make_float4(w4[0], w4[1], w4[2], w4[3]);
    }
    __syncthreads();
    #pragma unroll 4
    for(int i=0;i<m;i++){
      int row = ssrc[i];
      float w = swt[i][head];
      ushort4 u = *(const ushort4*)&hpu[(size_t)row*256 + 4*t];
      acc[0] += w*us2f(u.x); acc[1] += w*us2f(u.y);
      acc[2] += w*us2f(u.z); acc[3] += w*us2f(u.w);
    }
    __syncthreads();
  }
  #pragma unroll
  for(int o=1;o<64;o<<=1){
    #pragma unroll
    for(int h=0;h<4;h++){
      wsum[h] += __shfl_xor(wsum[h], o);
      dsum[h] += __shfl_xor(dsum[h], o);
    }
  }
  float alsnv[4] = {alsvn.x, alsvn.y, alsvn.z, alsvn.w};
  float aldnv[4] = {aldv.x, aldv.y, aldv.z, aldv.w};
  float sEh = sel4(wsum, head), sDh = sel4(dsum, head);
  float deg = (float)(e0 - s0);
  float sdot = deg > 0.f ? sDh/deg : 0.f;
  float sc = sel4(alsnv, head) + sel4(aldnv, head) + sdot;
  sc = sc > 0.f ? sc : NEG_SLOPE*sc;
  sc = fminf(sc, 30.f);
  float wself = expf(sc);
  ushort4 su = *(const ushort4*)&hpu[(size_t)n*256 + 4*t];
  float4 bi = *(const float4*)&bias256[4*t];
  float inv = 1.f/(sEh + wself);
  float4 o4;
  o4.x = (acc[0] + wself*us2f(su.x))*inv + bi.x;
  o4.y = (acc[1] + wself*us2f(su.y))*inv + bi.y;
  o4.z = (acc[2] + wself*us2f(su.z))*inv + bi.z;
  o4.w = (acc[3] + wself*us2f(su.w))*inv + bi.w;
  *(float4*)&out1[(size_t)n*256 + 4*t] = o4;
}

// ---------------- single-head GAT aggregate: ONE WAVE per node, 4 edges/iter ----------------
__global__ __launch_bounds__(64) void k_gat_agg1e(
    const int* __restrict__ rp, const int4* __restrict__ epk,
    const bf16* __restrict__ hp,                 // [N,64]
    const float* __restrict__ als, const float* __restrict__ ald,
    const float* __restrict__ bias64, float* __restrict__ out){
  int n = blockIdx.x; int t = threadIdx.x;
  int eg = t >> 4, cq = t & 15;
  __shared__ float sw[64];
  __shared__ int   ssrc[64];
  int s0 = rp[n], e0 = rp[n+1];
  if((unsigned)s0 > N_EDGES){ s0=0; e0=0; }
  if(e0 < s0 || (unsigned)e0 > N_EDGES) e0 = s0;
  float aldn = ald[n];
  float wsum_l = 0.f, dsum_l = 0.f;
  float acc[4] = {0.f,0.f,0.f,0.f};
  const unsigned short* hpu = (const unsigned short*)hp;
  for(int base = s0; base < e0; base += 64){
    int m = min(64, e0 - base);
    if(t < m){
      int4 pk = epk[base+t];
      int sn = pk.x; if((unsigned)sn >= N_NODES) sn = 0;
      ssrc[t] = sn;
      float ed = us2f((unsigned short)(pk.w & 0xffff));
      float sc = als[sn] + aldn + ed;
      sc = sc > 0.f ? sc : NEG_SLOPE*sc;
      sc = fminf(sc, 30.f);
      float w = expf(sc);
      sw[t] = w;
      wsum_l += w; dsum_l += ed;
    }
    __syncthreads();
    #pragma unroll 2
    for(int i=0;i<m;i+=4){
      int j = i + eg;
      if(j < m){
        int row = ssrc[j];
        float w = sw[j];
        ushort4 u = *(const ushort4*)&hpu[(size_t)row*64 + 4*cq];
        acc[0] += w*us2f(u.x); acc[1] += w*us2f(u.y);
        acc[2] += w*us2f(u.z); acc[3] += w*us2f(u.w);
      }
    }
    __syncthreads();
  }
  #pragma unroll
  for(int o=1;o<64;o<<=1){ wsum_l += __shfl_xor(wsum_l, o); dsum_l += __shfl_xor(dsum_l, o); }
  #pragma unroll
  for(int q=0;q<4;q++){ acc[q] += __shfl_xor(acc[q], 16); acc[q] += __shfl_xor(acc[q], 32); }
  if(t < 16){
    float deg = (float)(e0 - s0);
    float sdot = deg > 0.f ? dsum_l/deg : 0.f;
    float sc = als[n] + aldn + sdot;
    sc = sc > 0.f ? sc : NEG_SLOPE*sc;
    sc = fminf(sc, 30.f);
    float wself = expf(sc);
    ushort4 su = *(const ushort4*)&hpu[(size_t)n*64 + 4*cq];
    float4 bi = *(const float4*)&bias64[4*cq];
    float inv = 1.f/(wsum_l + wself);
    float4 o4;
    o4.x = (acc[0] + wself*us2f(su.x))*inv + bi.x;
    o4.y = (acc[1] + wself*us2f(su.y))*inv + bi.y;
    o4.z = (acc[2] + wself*us2f(su.z))*inv + bi.z;
    o4.w = (acc[3] + wself*us2f(su.w))*inv + bi.w;
    *(float4*)&out[(size_t)n*64 + 4*cq] = o4;
  }
}

// ---------------- GCN aggregate: ONE WAVE per node, 4 edges/iter ----------------
__global__ __launch_bounds__(64) void k_gcn_agg(
    const int* __restrict__ rp, const int4* __restrict__ epk,
    const float* __restrict__ dinv, const bf16* __restrict__ gp,
    const float* __restrict__ bias, float* __restrict__ out){
  int n = blockIdx.x; int t = threadIdx.x;
  int eg = t >> 4, cq = t & 15;
  __shared__ float sw[64];
  __shared__ int   ssrc[64];
  int s0 = rp[n], e0 = rp[n+1];
  if((unsigned)s0 > N_EDGES){ s0=0; e0=0; }
  if(e0 < s0 || (unsigned)e0 > N_EDGES) e0 = s0;
  float dn = dinv[n];
  float acc[4] = {0.f,0.f,0.f,0.f};
  const unsigned short* gpu = (const unsigned short*)gp;
  for(int base = s0; base < e0; base += 64){
    int m = min(64, e0 - base);
    if(t < m){
      int sn = epk[base+t].x; if((unsigned)sn >= N_NODES) sn = 0;
      ssrc[t]=sn; sw[t]=dinv[sn];
    }
    __syncthreads();
    #pragma unroll 2
    for(int i=0;i<m;i+=4){
      int j = i + eg;
      if(j < m){
        int row = ssrc[j];
        float w = sw[j];
        ushort4 u = *(const ushort4*)&gpu[(size_t)row*64 + 4*cq];
        acc[0] += w*us2f(u.x); acc[1] += w*us2f(u.y);
        acc[2] += w*us2f(u.z); acc[3] += w*us2f(u.w);
      }
    }
    __syncthreads();
  }
  #pragma unroll
  for(int q=0;q<4;q++){ acc[q] += __shfl_xor(acc[q], 16); acc[q] += __shfl_xor(acc[q], 32); }
  if(t < 16){
    ushort4 su = *(const ushort4*)&gpu[(size_t)n*64 + 4*cq];
    float4 bi = *(const float4*)&bias[4*cq];
    float4 o4;
    o4.x = dn*(acc[0] + dn*us2f(su.x)) + bi.x;
    o4.y = dn*(acc[1] + dn*us2f(su.y)) + bi.y;
    o4.z = dn*(acc[2] + dn*us2f(su.z)) + bi.z;
    o4.w = dn*(acc[3] + dn*us2f(su.w)) + bi.w;
    *(float4*)&out[(size_t)n*64 + 4*cq] = o4;
  }
}

// ---------------- BN stats ----------------
template<int C>
__global__ void k_colstats(const float* __restrict__ X, float* __restrict__ sums){
  constexpr int RPB = 128;
  constexpr int RSTEP = 256 / C;
  int c = threadIdx.x % C;
  int r0 = threadIdx.x / C;
  int rbeg = blockIdx.x * RPB;
  int rend = min(N_NODES, rbeg + RPB);
  float s = 0.f, q = 0.f;
  for(int r = rbeg + r0; r < rend; r += RSTEP){
    float v = sane(X[(size_t)r*C + c]);
    s += v; q += v*v;
  }
  atomicAdd(&sums[c], s);
  atomicAdd(&sums[C + c], q);
}

// ---------------- mean pool with fused BN+ReLU ----------------
__global__ __launch_bounds__(64) void k_pool3(
    const float* __restrict__ h, const int* __restrict__ batch,
    const float* __restrict__ sums, const float* __restrict__ g4,
    const float* __restrict__ b4,
    float* __restrict__ psum, float* __restrict__ pcnt){
  int t = threadIdx.x;
  int n0 = blockIdx.x * 256;
  int n1 = min(N_NODES, n0 + 256);
  if(n0 >= n1) return;
  const float invN = 1.0f / (float)N_NODES;
  float mean = sums[t]*invN;
  float var = fmaxf(sums[64+t]*invN - mean*mean, 0.f);
  float rstd = rsqrtf(var + BN_EPS);
  float gg = g4[t], bb = b4[t];
  int cur = batch[n0]; if((unsigned)cur >= N_GRAPHS) cur = 0;
  float acc = 0.f; int cl = 0;
  for(int n = n0; n < n1; n++){
    int g = batch[n]; if((unsigned)g >= N_GRAPHS) g = 0;
    if(g != cur){
      atomicAdd(&psum[cur*64 + t], acc);
      if(t == 0) atomicAdd(&pcnt[cur], (float)cl);
      acc = 0.f; cl = 0; cur = g;
    }
    float y = (sane(h[(size_t)n*64 + t])-mean)*rstd*gg + bb;
    acc += fmaxf(y, 0.f);
    cl++;
  }
  atomicAdd(&psum[cur*64 + t], acc);
  if(t == 0) atomicAdd(&pcnt[cur], (float)cl);
}

// ---------------- head MLPs + output ----------------
__device__ __forceinline__ void stO(void* o, size_t i, float v, int m){
  if(m) ((float*)o)[i] = v; else ((bf16*)o)[i] = f2b(v);
}

__global__ __launch_bounds__(128) void k_head(
    const float* __restrict__ psum, const float* __restrict__ pcnt,
    const float* __restrict__ exf,
    const float* __restrict__ Wex1, const float* __restrict__ bex1,
    const float* __restrict__ Wex2, const float* __restrict__ bex2,
    const float* __restrict__ Wc1, const float* __restrict__ bc1,
    const float* __restrict__ Wc2, const float* __restrict__ bc2,
    const int* __restrict__ mode, void* __restrict__ dout){
  int g = blockIdx.x; int t = threadIdx.x;
  int m0 = *mode;
  __shared__ float ci[128];
  __shared__ float e1[64];
  __shared__ float comb[128];
  __shared__ float red[128];
  if(t < 64){
    float c = fmaxf(pcnt[g], 1.f);
    float xp = sane(psum[g*64 + t]) / c;
    ci[t] = xp;
    stO(dout, 256 + (size_t)g*64 + t, xp, m0);
  } else {
    int j = t - 64;
    float s = bex1[j];
    for(int k=0;k<32;k++) s += exf[g*32 + k] * Wex1[k*64 + j];
    e1[j] = fmaxf(s, 0.f);
  }
  __syncthreads();
  if(t >= 64){
    int j = t - 64;
    float s = bex2[j];
    for(int k=0;k<64;k++) s += e1[k] * Wex2[k*64 + j];
    ci[64 + j] = fmaxf(s, 0.f);
  }
  __syncthreads();
  {
    float s = bc1[t];
    for(int k=0;k<128;k++) s += ci[k] * Wc1[k*128 + t];
    s = fmaxf(s, 0.f);
    comb[t] = s;
    stO(dout, 256 + 16384 + (size_t)g*128 + t, s, m0);
  }
  __syncthreads();
  red[t] = comb[t] * Wc2[t];
  __syncthreads();
  for(int o=64;o>0;o>>=1){ if(t<o) red[t]+=red[t+o]; __syncthreads(); }
  if(t==0) stO(dout, g, red[0] + bc2[0], m0);
}

// ---------------- launch ----------------
extern "C" void kernel_launch(void* const* d_in, const int* in_sizes, int n_in,
                              void* d_out, int out_size, void* d_ws, size_t ws_size,
                              hipStream_t stream){
  const void* x    = d_in[0];
  const void* ea   = d_in[1];
  const int* ei    = (const int*)d_in[3];
  const int* batch = (const int*)d_in[4];
  const int* src = ei;
  const int* dst = ei + N_EDGES;

  char* base = (char*)d_ws;
  size_t off = 0;
  auto alloc = [&](size_t bytes) -> void* {
    void* r = base + off;
    off += (bytes + 255) & ~(size_t)255;
    return r;
  };
  int*   cnt    = (int*)  alloc((size_t)N_NODES*4);
  int*   fill   = (int*)  alloc((size_t)N_NODES*4);
  float* bnstat = (float*)alloc(4096);
  float* pool   = (float*)alloc((size_t)(N_GRAPHS*64 + N_GRAPHS)*4);
  size_t zbytes = off;
  int*   rp      = (int*)  alloc((size_t)(N_NODES+1)*4);
  int*   bsum    = (int*)  alloc(256*4);
  int*   bofs    = (int*)  alloc(256*4);
  int4*  epk     = (int4*) alloc((size_t)N_EDGES*16);
  float* dinv    = (float*)alloc((size_t)N_NODES*4);
  float* w_e     = (float*)alloc(64*4);
  float* als4    = (float*)alloc((size_t)N_NODES*4*4);
  float* ald4    = (float*)alloc((size_t)N_NODES*4*4);
  int*   mode    = (int*)  alloc(8);
  float* wbank   = (float*)alloc(80000*4);
  bf16*  hp      = (bf16*) alloc((size_t)N_NODES*256*2);
  float* out1    = (float*)alloc((size_t)N_NODES*256*4);

  float* out2 = out1;
  float* out3 = out1 + (size_t)N_NODES*64;
  float* out4 = out1 + (size_t)N_NODES*128;
  float* bn1 = bnstat;
  float* bn2 = bnstat + 512;
  float* bn3 = bnstat + 640;
  float* bn4 = bnstat + 768;
  float* psum = pool;
  float* pcnt = pool + N_GRAPHS*64;
  int* fone = mode + 1;

  const int segidx[NSEG] = {2, 5,6,7,8,9,10,11,12, 13,14,15,16,17,18,19,20,
                            21,22,23,24, 25,26,27,28, 29,30,31,32, 33,34,35,36};
  const int segn[NSEG] = {8192, 16384,256,256,2048,256,256,256,256,
                          16384,64,64,512,64,64,64,64,
                          4096,64,64,64, 4096,64,64,64,
                          2048,64,4096,64, 16384,128,128,1};
  Bank bk;
  int offs[NSEG]; int acc0 = 0;
  for(int i=0;i<NSEG;i++){ bk.p[i]=d_in[segidx[i]]; bk.n[i]=segn[i]; bk.off[i]=acc0; offs[i]=acc0; acc0+=segn[i]; }
  const float* f_exf = wbank + offs[0];
  const float* fW1 = wbank+offs[1]; const float* fas1 = wbank+offs[2]; const float* fad1 = wbank+offs[3];
  const float* fWe1= wbank+offs[4]; const float* fae1 = wbank+offs[5]; const float* fb1  = wbank+offs[6];
  const float* fg1 = wbank+offs[7]; const float* fbe1 = wbank+offs[8];
  const float* fW2 = wbank+offs[9]; const float* fas2 = wbank+offs[10]; const float* fad2 = wbank+offs[11];
  const float* fWe2= wbank+offs[12]; const float* fae2 = wbank+offs[13]; const float* fb2 = wbank+offs[14];
  const float* fg2 = wbank+offs[15]; const float* fbe2 = wbank+offs[16];
  const float* fWg1= wbank+offs[17]; const float* fbg1 = wbank+offs[18]; const float* fg3 = wbank+offs[19];
  const float* fbe3= wbank+offs[20];
  const float* fWg2= wbank+offs[21]; const float* fbg2 = wbank+offs[22]; const float* fg4 = wbank+offs[23];
  const float* fbe4= wbank+offs[24];
  const float* fWex1=wbank+offs[25]; const float* fbex1= wbank+offs[26];
  const float* fWex2=wbank+offs[27]; const float* fbex2= wbank+offs[28];
  const float* fWc1= wbank+offs[29]; const float* fbc1 = wbank+offs[30];
  const float* fWc2= wbank+offs[31]; const float* fbc2 = wbank+offs[32];

  const int nbN  = (N_NODES + 255)/256;
  const int nbE  = (N_EDGES + 255)/256;
  const int nbT  = (N_NODES + 63)/64;

  hipMemsetAsync(d_ws, 0, zbytes, stream);
  k_detect<<<1,64,0,stream>>>(x, mode);
  {
    dim3 g((16384+255)/256, NSEG);
    k_convert<<<g,256,0,stream>>>(bk, mode, wbank);
  }
  k_we<<<1,64,0,stream>>>(fWe1, fae1, fWe2, fae2, w_e);
  k_count<<<nbE,256,0,stream>>>(dst, cnt);
  k_blocksum<<<nbN,256,0,stream>>>(cnt, bsum);
  k_scan_bsum<<<1,256,0,stream>>>(bsum, bofs, nbN);
  k_scan_write<<<nbN,256,0,stream>>>(cnt, bofs, rp);
  k_fill<<<nbE,256,0,stream>>>(src, dst, rp, fill, ea, mode, w_e, epk);
  k_dinv<<<nbN,256,0,stream>>>(rp, dinv);

  // GAT layer 1 (4 heads fused)
  {
    dim3 g(nbT, 4);
    k_gemm_t<64,true,false><<<g,256,0,stream>>>(x, 64, mode, fW1, 256, 0, hp, 256, 0, N_NODES,
                                                nullptr, nullptr, nullptr);
  }
  k_al4<<<(N_NODES*4+255)/256,256,0,stream>>>(hp, fas1, fad1, als4, ald4);
  k_gat_agg4<<<N_NODES,64,0,stream>>>(rp, epk, hp, als4, ald4, fb1, out1);
  k_colstats<256><<<(N_NODES+127)/128,256,0,stream>>>(out1, bn1);

  // GAT layer 2 (1 head) — BN1+ReLU fused into A-staging
  k_gemm_t<256,true,true><<<nbT,256,0,stream>>>(out1, 256, fone, fW2, 64, 0, hp, 64, 0, N_NODES,
                                                bn1, fg1, fbe1);
  k_al1<<<nbN,256,0,stream>>>(hp, fas2, fad2, als4, ald4);
  k_gat_agg1e<<<N_NODES,64,0,stream>>>(rp, epk, hp, als4, ald4, fb2, out2);
  k_colstats<64><<<(N_NODES+127)/128,256,0,stream>>>(out2, bn2);

  // GCN layer 1 — BN2+ReLU fused
  k_gemm_t<64,true,true><<<nbT,256,0,stream>>>(out2, 64, fone, fWg1, 64, 0, hp, 64, 0, N_NODES,
                                               bn2, fg2, fbe2);
  k_gcn_agg<<<N_NODES,64,0,stream>>>(rp, epk, dinv, hp, fbg1, out3);
  k_colstats<64><<<(N_NODES+127)/128,256,0,stream>>>(out3, bn3);

  // GCN layer 2 — BN3+ReLU fused
  k_gemm_t<64,true,true><<<nbT,256,0,stream>>>(out3, 64, fone, fWg2, 64, 0, hp, 64, 0, N_NODES,
                                               bn3, fg3, fbe3);
  k_gcn_agg<<<N_NODES,64,0,stream>>>(rp, epk, dinv, hp, fbg2, out4);
  k_colstats<64><<<(N_NODES+127)/128,256,0,stream>>>(out4, bn4);

  // pool (BN4+ReLU fused) + head
  k_pool3<<<nbN,64,0,stream>>>(out4, batch, bn4, fg4, fbe4, psum, pcnt);
  k_head<<<N_GRAPHS,128,0,stream>>>(psum, pcnt, f_exf, fWex1, fbex1, fWex2, fbex2,
                                    fWc1, fbc1, fWc2, fbc2, mode, d_out);
}